// Round 13
// baseline (4155.674 us; speedup 1.0000x reference)
//
#include <hip/hip_runtime.h>

#define NB_V 65536
#define TOPK 4096
#define FPSK 2048

typedef short bf16x8 __attribute__((ext_vector_type(8)));
typedef float f32x4 __attribute__((ext_vector_type(4)));

// ---------------------------------------------------------------------------
// DUAL GEMM: blocks [0, NCB) = cls f64-accum GEMM (64x128 tile, 4x8 f64 acc,
// f64 LDS staging — cvt once at stage time, conflict-engineered layouts:
// A[64][33] f64 (broadcast reads), W group-stride-10 swizzle (<=2-way b128)).
// Pure-k-order fma chain on identical values -> selection-safe.
// blocks [NCB, ...) = offset bf16-MFMA GEMM (validated verbatim).
// Both fold BN stats partials into the epilogue.
// ---------------------------------------------------------------------------
__global__ __launch_bounds__(256, 2) void k_dualgemm(
    const float* __restrict__ A, const float* __restrict__ Wcls,
    const float* __restrict__ Woff, float* __restrict__ Hcls,
    float* __restrict__ Hoff, double* __restrict__ part_cls,
    float2* __restrict__ part_off, int N) {
  __shared__ __align__(16) char smem[67584];
  const int tid = threadIdx.x;
  const int NCB = (N >> 6) << 1;   // (N/64)*2 cls blocks

  if ((int)blockIdx.x < NCB) {
    // ----------------------------- cls f64 GEMM ---------------------------
    double(*Asm)[33] = (double(*)[33])smem;              // [64][33] f64, 16896 B
    double* BfF = (double*)(smem + 16896);               // [32][160] f64, 40960 B
    const int tx = tid & 15, ty = tid >> 4;
    const int cb = blockIdx.x & 1;
    const int rb = blockIdx.x >> 1;
    double acc[4][8];
#pragma unroll
    for (int i = 0; i < 4; ++i)
#pragma unroll
      for (int j = 0; j < 8; ++j) acc[i][j] = 0.0;

    for (int kc = 0; kc < 256; kc += 32) {
#pragma unroll
      for (int l = 0; l < 8; ++l) {
        int f = tid + 256 * l;
        int r = f >> 5, c = f & 31;
        Asm[r][c] = (double)A[(size_t)(rb * 64 + r) * 256 + kc + c];
      }
#pragma unroll
      for (int l = 0; l < 16; ++l) {
        int f = tid + 256 * l;
        int kr = f >> 7, c = f & 127;
        BfF[kr * 160 + (c >> 3) * 10 + (c & 7)] =
            (double)Wcls[(size_t)(kc + kr) * 256 + cb * 128 + c];
      }
      __syncthreads();
#pragma unroll 4
      for (int kk = 0; kk < 32; ++kk) {
        double a0[4];
#pragma unroll
        for (int i = 0; i < 4; ++i) a0[i] = Asm[ty + 16 * i][kk];
        const double* bR = BfF + kk * 160 + tx * 10;
        double2 b01 = *reinterpret_cast<const double2*>(bR);
        double2 b23 = *reinterpret_cast<const double2*>(bR + 2);
        double2 b45 = *reinterpret_cast<const double2*>(bR + 4);
        double2 b67 = *reinterpret_cast<const double2*>(bR + 6);
        double b0[8] = {b01.x, b01.y, b23.x, b23.y, b45.x, b45.y, b67.x, b67.y};
#pragma unroll
        for (int i = 0; i < 4; ++i)
#pragma unroll
          for (int j = 0; j < 8; ++j) acc[i][j] = fma(a0[i], b0[j], acc[i][j]);
      }
      __syncthreads();
    }
    double s[8], q[8];
#pragma unroll
    for (int j = 0; j < 8; ++j) { s[j] = 0.0; q[j] = 0.0; }
#pragma unroll
    for (int i = 0; i < 4; ++i) {
      float hv[8];
#pragma unroll
      for (int j = 0; j < 8; ++j) {
        hv[j] = (float)acc[i][j];
        double d = (double)hv[j];
        s[j] += d;
        q[j] = fma(d, d, q[j]);
      }
      size_t base = (size_t)(rb * 64 + ty + 16 * i) * 256 + cb * 128 + tx * 8;
      *reinterpret_cast<float4*>(&Hcls[base]) = make_float4(hv[0], hv[1], hv[2], hv[3]);
      *reinterpret_cast<float4*>(&Hcls[base + 4]) = make_float4(hv[4], hv[5], hv[6], hv[7]);
    }
    __syncthreads();  // reuse LDS
    double(*ps)[128] = (double(*)[128])smem;              // [16][128]
    double(*pq)[128] = (double(*)[128])(smem + 16384);
#pragma unroll
    for (int j = 0; j < 8; ++j) {
      ps[ty][tx * 8 + j] = s[j];
      pq[ty][tx * 8 + j] = q[j];
    }
    __syncthreads();
    if (tid < 128) {
      double S = 0.0, Q = 0.0;
#pragma unroll
      for (int t = 0; t < 16; ++t) { S += ps[t][tid]; Q += pq[t][tid]; }
      part_cls[(size_t)blockIdx.x * 256 + tid * 2] = S;
      part_cls[(size_t)blockIdx.x * 256 + tid * 2 + 1] = Q;
    }
  } else {
    // --------------------- offset bf16 GEMM (validated) -------------------
    unsigned short(*As)[264] = (unsigned short(*)[264])smem;
    unsigned short(*Bs)[264] = (unsigned short(*)[264])(smem + 33792);
    const int gb = blockIdx.x - NCB;
    const int cb = gb & 3;
    const int rb = gb >> 2;
#pragma unroll
    for (int l = 0; l < 16; ++l) {
      int f = tid + 256 * l;
      int r = f >> 6, c4 = (f & 63) << 2;
      float4 v = *reinterpret_cast<const float4*>(&A[(size_t)(rb * 64 + r) * 256 + c4]);
      ushort4 u;
      u.x = (unsigned short)(__float_as_uint(v.x) >> 16);
      u.y = (unsigned short)(__float_as_uint(v.y) >> 16);
      u.z = (unsigned short)(__float_as_uint(v.z) >> 16);
      u.w = (unsigned short)(__float_as_uint(v.w) >> 16);
      *reinterpret_cast<ushort4*>(&As[r][c4]) = u;
    }
    {
      const int c = tid & 63;
      const int kg = tid >> 6;
#pragma unroll
      for (int j = 0; j < 16; ++j) {
        int k0 = kg * 64 + j * 4;
        ushort4 u;
        u.x = (unsigned short)(__float_as_uint(Woff[(size_t)(k0 + 0) * 256 + cb * 64 + c]) >> 16);
        u.y = (unsigned short)(__float_as_uint(Woff[(size_t)(k0 + 1) * 256 + cb * 64 + c]) >> 16);
        u.z = (unsigned short)(__float_as_uint(Woff[(size_t)(k0 + 2) * 256 + cb * 64 + c]) >> 16);
        u.w = (unsigned short)(__float_as_uint(Woff[(size_t)(k0 + 3) * 256 + cb * 64 + c]) >> 16);
        *reinterpret_cast<ushort4*>(&Bs[c][k0]) = u;
      }
    }
    __syncthreads();
    const int lane = tid & 63, w = tid >> 6;
    const int m = lane & 15, kq = lane >> 4;
    f32x4 acc[4];
#pragma unroll
    for (int s = 0; s < 4; ++s) acc[s] = (f32x4){0.f, 0.f, 0.f, 0.f};
#pragma unroll
    for (int k0 = 0; k0 < 256; k0 += 32) {
      bf16x8 a = *reinterpret_cast<const bf16x8*>(&As[w * 16 + m][k0 + kq * 8]);
#pragma unroll
      for (int s = 0; s < 4; ++s) {
        bf16x8 bfr = *reinterpret_cast<const bf16x8*>(&Bs[s * 16 + m][k0 + kq * 8]);
        acc[s] = __builtin_amdgcn_mfma_f32_16x16x32_bf16(a, bfr, acc[s], 0, 0, 0);
      }
    }
    double cs[4], cq[4];
#pragma unroll
    for (int s = 0; s < 4; ++s) { cs[s] = 0.0; cq[s] = 0.0; }
#pragma unroll
    for (int s = 0; s < 4; ++s)
#pragma unroll
      for (int i = 0; i < 4; ++i) {
        float hv = acc[s][i];
        Hoff[(size_t)(rb * 64 + w * 16 + kq * 4 + i) * 256 + cb * 64 + s * 16 + m] = hv;
        double d = (double)hv;
        cs[s] += d;
        cq[s] = fma(d, d, cq[s]);
      }
    __syncthreads();  // reuse LDS
    double(*ps)[64] = (double(*)[64])smem;              // [16][64]
    double(*pq)[64] = (double(*)[64])(smem + 8192);
#pragma unroll
    for (int s = 0; s < 4; ++s) {
      ps[w * 4 + kq][s * 16 + m] = cs[s];
      pq[w * 4 + kq][s * 16 + m] = cq[s];
    }
    __syncthreads();
    if (tid < 64) {
      double S = 0.0, Q = 0.0;
#pragma unroll
      for (int t = 0; t < 16; ++t) { S += ps[t][tid]; Q += pq[t][tid]; }
      part_off[(size_t)gb * 64 + tid] = make_float2((float)S, (float)Q);
    }
  }
}

// ---------------------------------------------------------------------------
// Stats finalize, parallel (validated R12).
// ---------------------------------------------------------------------------
__global__ __launch_bounds__(256) void k_fins(const double* __restrict__ part_cls,
                                              const float2* __restrict__ part_off,
                                              const float* __restrict__ g_cls,
                                              const float* __restrict__ be_cls,
                                              const float* __restrict__ g_off,
                                              const float* __restrict__ be_off,
                                              double* __restrict__ a_cls,
                                              double* __restrict__ c_cls,
                                              double* __restrict__ a_off,
                                              double* __restrict__ c_off, int N) {
  __shared__ double ls[256], lq[256];
  const int tid = threadIdx.x;
  const int nrb = N >> 6;
  double S = 0.0, Q = 0.0;
  if ((int)blockIdx.x < 256) {
    const int c = blockIdx.x;
    const int cbb = c >> 7, cl = c & 127;
    for (int m = 0; m < nrb / 256; ++m) {
      int rb = tid + 256 * m;
      const double* p = part_cls + ((size_t)(rb * 2 + cbb) * 256 + cl * 2);
      S += p[0];
      Q += p[1];
    }
  } else {
    const int c = blockIdx.x - 256;
    const int ccb = c >> 6, cl = c & 63;
    for (int m = 0; m < nrb / 256; ++m) {
      int r2 = tid + 256 * m;
      float2 p = part_off[(size_t)(r2 * 4 + ccb) * 64 + cl];
      S += (double)p.x;
      Q += (double)p.y;
    }
  }
  ls[tid] = S;
  lq[tid] = Q;
  __syncthreads();
  for (int st = 128; st; st >>= 1) {
    if (tid < st) {
      ls[tid] += ls[tid + st];
      lq[tid] += lq[tid + st];
    }
    __syncthreads();
  }
  if (tid == 0) {
    double mean = ls[0] / (double)N;
    double var = lq[0] / (double)N - mean * mean;
    if ((int)blockIdx.x < 256) {
      const int c = blockIdx.x;
      double a = (double)g_cls[c] / sqrt(var + 1e-5);
      a_cls[c] = a;
      c_cls[c] = (double)be_cls[c] - mean * a;
    } else {
      const int c = blockIdx.x - 256;
      double a = (double)g_off[c] / sqrt(var + 1e-5);
      a_off[c] = a;
      c_off[c] = (double)be_off[c] - mean * a;
    }
  }
}

// ---------------------------------------------------------------------------
// cls-side fuse: BN+ReLU+layer2 on Hcls -> seeds, seed_cls, sort keys.
// ---------------------------------------------------------------------------
__global__ __launch_bounds__(256) void k_fuse_cls(const float* __restrict__ Hcls,
                                                  const float* __restrict__ xyz,
                                                  const float* __restrict__ w_cls2,
                                                  const float* __restrict__ b_cls2,
                                                  const double* __restrict__ aarr,
                                                  const double* __restrict__ carr,
                                                  float* __restrict__ out_seeds,
                                                  float* __restrict__ out_cls,
                                                  unsigned long long* __restrict__ keys,
                                                  int N) {
  __shared__ double sa[256], sc[256];
  __shared__ double w2[256][3];
  const int tid = threadIdx.x;
  {
    sa[tid] = aarr[tid];
    sc[tid] = carr[tid];
#pragma unroll
    for (int k = 0; k < 3; ++k) w2[tid][k] = (double)w_cls2[tid * 3 + k];
  }
  __syncthreads();
  const int lane = tid & 63, wid = tid >> 6;
  const int gw = blockIdx.x * 4 + wid;
  for (int r = gw; r < N; r += 4096) {
    double pc0 = 0, pc1 = 0, pc2 = 0;
#pragma unroll
    for (int q = 0; q < 4; ++q) {
      int c = lane + 64 * q;
      double h2 = (double)Hcls[(size_t)r * 256 + c];
      double v2 = fma(h2, sa[c], sc[c]);
      v2 = v2 > 0.0 ? v2 : 0.0;
      pc0 = fma(v2, w2[c][0], pc0);
      pc1 = fma(v2, w2[c][1], pc1);
      pc2 = fma(v2, w2[c][2], pc2);
    }
#pragma unroll
    for (int off = 32; off; off >>= 1) {
      pc0 += __shfl_xor(pc0, off);
      pc1 += __shfl_xor(pc1, off);
      pc2 += __shfl_xor(pc2, off);
    }
    if (lane == 0) {
      float x = xyz[(size_t)r * 3], y = xyz[(size_t)r * 3 + 1], z = xyz[(size_t)r * 3 + 2];
      float bs = (float)(r >> 16);
      out_seeds[(size_t)r * 4 + 0] = bs;
      out_seeds[(size_t)r * 4 + 1] = x;
      out_seeds[(size_t)r * 4 + 2] = y;
      out_seeds[(size_t)r * 4 + 3] = z;
      double c0 = pc0 + (double)b_cls2[0];
      double c1 = pc1 + (double)b_cls2[1];
      double c2v = pc2 + (double)b_cls2[2];
      out_cls[(size_t)r * 3 + 0] = (float)c0;
      out_cls[(size_t)r * 3 + 1] = (float)c1;
      out_cls[(size_t)r * 3 + 2] = (float)c2v;
      double s = c0 > c1 ? c0 : c1;
      s = s > c2v ? s : c2v;
      long long bits = __double_as_longlong(s);
      unsigned long long key =
          bits >= 0 ? ((unsigned long long)bits | 0x8000000000000000ull) : ~((unsigned long long)bits);
      keys[r] = key;
    }
  }
}

// ---------------------------------------------------------------------------
// Per-batch top-4096 radix select + bitonic sort (validated).
// ---------------------------------------------------------------------------
__global__ __launch_bounds__(1024) void k_topk(const unsigned long long* __restrict__ keys,
                                               unsigned int* __restrict__ topk) {
  const int b = blockIdx.x;
  const unsigned long long* K = keys + (size_t)b * NB_V;
  __shared__ unsigned int hist[256];
  __shared__ unsigned long long pfx_s;
  __shared__ int want_s;
  __shared__ unsigned long long skey[TOPK];
  __shared__ unsigned int sidx[TOPK];
  __shared__ int cnt_hi, cnt_eq;
  __shared__ unsigned int eq_idx[1024];
  const int tid = threadIdx.x;
  const int lane = tid & 63;
  if (tid == 0) { pfx_s = 0ull; want_s = TOPK; }
  __syncthreads();
  for (int p = 0; p < 8; ++p) {
    const int shift = 56 - 8 * p;
    if (tid < 256) hist[tid] = 0;
    __syncthreads();
    unsigned long long pfx = pfx_s;
    for (int i = tid; i < NB_V; i += 1024) {
      unsigned long long k = K[i];
      bool ok;
      if (p == 0) ok = true;
      else ok = ((k >> (shift + 8)) == (pfx >> (shift + 8)));
      unsigned bin = ok ? (unsigned)((k >> shift) & 255u) : 0xFFFFFFFFu;
      unsigned long long okm = __ballot(ok);
      if (okm) {
        int leader = __ffsll((unsigned long long)okm) - 1;
        unsigned pb = __shfl(bin, leader);
        unsigned long long m = __ballot(ok && bin == pb);
        if (lane == leader) atomicAdd(&hist[pb], (unsigned)__popcll(m));
        if (ok && bin != pb) atomicAdd(&hist[bin], 1u);
      }
    }
    __syncthreads();
    if (tid == 0) {
      int want = want_s;
      int cum = 0, d = 255;
      for (; d >= 0; --d) {
        int c = (int)hist[d];
        if (cum + c >= want) break;
        cum += c;
      }
      want_s = want - cum;
      pfx_s = pfx_s | ((unsigned long long)d << shift);
    }
    __syncthreads();
  }
  const unsigned long long Kthr = pfx_s;
  const int T = want_s;
  if (tid == 0) { cnt_hi = 0; cnt_eq = 0; }
  __syncthreads();
  for (int i = tid; i < NB_V; i += 1024) {
    unsigned long long k = K[i];
    if (k > Kthr) {
      int pos = atomicAdd(&cnt_hi, 1);
      skey[pos] = k;
      sidx[pos] = (unsigned)i;
    } else if (k == Kthr) {
      int pos = atomicAdd(&cnt_eq, 1);
      if (pos < 1024) eq_idx[pos] = (unsigned)i;
    }
  }
  __syncthreads();
  if (tid == 0) {
    int m = cnt_eq; if (m > 1024) m = 1024;
    for (int a2 = 1; a2 < m; ++a2) {
      unsigned v = eq_idx[a2];
      int b2 = a2 - 1;
      while (b2 >= 0 && eq_idx[b2] > v) { eq_idx[b2 + 1] = eq_idx[b2]; --b2; }
      eq_idx[b2 + 1] = v;
    }
    for (int t = 0; t < T; ++t) { skey[cnt_hi + t] = Kthr; sidx[cnt_hi + t] = eq_idx[t]; }
  }
  __syncthreads();
  for (int k2 = 2; k2 <= TOPK; k2 <<= 1) {
    for (int j = k2 >> 1; j > 0; j >>= 1) {
      for (int i = tid; i < TOPK; i += 1024) {
        int ix = i ^ j;
        if (ix > i) {
          unsigned long long ka = skey[i], kb = skey[ix];
          unsigned int ia = sidx[i], ib = sidx[ix];
          bool a_first = (ka > kb) || (ka == kb && ia < ib);
          bool up = (i & k2) == 0;
          if (up ? !a_first : a_first) {
            skey[i] = kb; skey[ix] = ka;
            sidx[i] = ib; sidx[ix] = ia;
          }
        }
      }
      __syncthreads();
    }
  }
  for (int i = tid; i < TOPK; i += 1024) topk[(size_t)b * TOPK + i] = sidx[i];
}

// ---------------------------------------------------------------------------
// FUSED2 (512 threads): blocks 0..3 = D-FPS, 8 pts/thread, 2 waves/SIMD so
// dependent reduce tails interleave (DPP reduce is VALU — no LDS storm).
// blocks 4..515 = fuse_off (8 waves each). 82944 B LDS -> 1 block/CU.
// Selection semantics identical: p = tid + 512*j ascending; strict > keeps
// min pos in-thread; all merges tie -> min pos.
// ---------------------------------------------------------------------------
template <int CTRL>
__device__ __forceinline__ void dpp_merge2(unsigned long long& v, int& p) {
  unsigned lo = (unsigned)v, hi = (unsigned)(v >> 32);
  unsigned olo = (unsigned)__builtin_amdgcn_update_dpp(0, (int)lo, CTRL, 0xF, 0xF, false);
  unsigned ohi = (unsigned)__builtin_amdgcn_update_dpp(0, (int)hi, CTRL, 0xF, 0xF, false);
  int op = __builtin_amdgcn_update_dpp(0, p, CTRL, 0xF, 0xF, false);
  unsigned long long ov = ((unsigned long long)ohi << 32) | (unsigned long long)olo;
  bool t = (ov > v) || (ov == v && op < p);
  v = t ? ov : v;
  p = t ? op : p;
}

__device__ __forceinline__ void shfl_merge2(unsigned long long& v, int& p, int mask) {
  unsigned long long ov = __shfl_xor(v, mask);
  int op = __shfl_xor(p, mask);
  bool t = (ov > v) || (ov == v && op < p);
  v = t ? ov : v;
  p = t ? op : p;
}

#define FPS_REP8(M) M(0) M(1) M(2) M(3) M(4) M(5) M(6) M(7)

__global__ __launch_bounds__(512, 1) void k_fused2(const float* __restrict__ xyz,
                                                   const unsigned int* __restrict__ topk,
                                                   unsigned int* __restrict__ fpspos,
                                                   const float* __restrict__ Hoff,
                                                   const double* __restrict__ a_off,
                                                   const double* __restrict__ c_off,
                                                   const float* __restrict__ w_off2,
                                                   const float* __restrict__ b_off2,
                                                   float* __restrict__ out_votes, int N) {
  __shared__ __align__(16) char smem[82944];  // > 80 KB -> 1 block/CU
  const int tid = threadIdx.x;

  if (blockIdx.x < 4) {
    // ------------------------------ FPS path ------------------------------
    float4* cpos = (float4*)smem;  // 64 KB
    ulonglong2(*wv)[8] = (ulonglong2(*)[8])(smem + 65536);   // [2][8]
    float4(*wc)[8] = (float4(*)[8])(smem + 65536 + 256);     // [2][8]
    const int b = blockIdx.x;

#define FPS_DECL(J) float x##J, y##J, z##J; double d##J;
    FPS_REP8(FPS_DECL)

#define FPS_INIT(J) { \
    int p = tid + 512 * (J); \
    unsigned idx = topk[(size_t)b * TOPK + p]; \
    size_t base = ((size_t)b * NB_V + idx) * 3; \
    x##J = xyz[base]; y##J = xyz[base + 1]; z##J = xyz[base + 2]; \
    d##J = 1e10; \
    cpos[p] = make_float4(x##J, y##J, z##J, 0.0f); }
    FPS_REP8(FPS_INIT)

    if (tid == 0) {
      wc[0][0] = make_float4(x0, y0, z0, 0.0f);
      fpspos[(size_t)b * FPSK] = 0u;
    }
    __syncthreads();
    float4 s0 = wc[0][0];
    float sx = s0.x, sy = s0.y, sz = s0.z;
    const int lane = tid & 63, wid = tid >> 6;

    for (int it = 1; it < FPSK; ++it) {
      const int par = it & 1;
      double lx = (double)sx, ly = (double)sy, lz = (double)sz;
      unsigned long long cv0, cv1;
      int cp0, cp1;
#define FPS_UPD(J) { \
    double dx = (double)x##J - lx; \
    double dy = (double)y##J - ly; \
    double dz = (double)z##J - lz; \
    double dd = __dadd_rn(__dadd_rn(__dmul_rn(dx, dx), __dmul_rn(dy, dy)), __dmul_rn(dz, dz)); \
    d##J = fmin(d##J, dd); \
    unsigned long long db = (unsigned long long)__double_as_longlong(d##J); \
    if ((J) == 0) { cv0 = db; cp0 = tid; } \
    else if ((J) == 1) { cv1 = db; cp1 = tid + 512; } \
    else if (((J) & 1) == 0) { bool g = db > cv0; cv0 = g ? db : cv0; cp0 = g ? (tid + 512 * (J)) : cp0; } \
    else { bool g = db > cv1; cv1 = g ? db : cv1; cp1 = g ? (tid + 512 * (J)) : cp1; } }
      FPS_REP8(FPS_UPD)
      {  // merge odd chain into even (tie -> min pos)
        bool g = (cv1 > cv0) || (cv1 == cv0 && cp1 < cp0);
        cv0 = g ? cv1 : cv0;
        cp0 = g ? cp1 : cp0;
      }
      dpp_merge2<0xB1>(cv0, cp0);   // quad_perm xor1
      dpp_merge2<0x4E>(cv0, cp0);   // quad_perm xor2
      dpp_merge2<0x124>(cv0, cp0);  // row_ror:4
      dpp_merge2<0x128>(cv0, cp0);  // row_ror:8 -> row winner in all 16 lanes
      shfl_merge2(cv0, cp0, 16);
      shfl_merge2(cv0, cp0, 32);    // wave winner in all 64 lanes
      float4 wpos = cpos[cp0];      // uniform addr -> broadcast ds_read_b128
      if (lane == 0) {
        wv[par][wid] = make_ulonglong2(cv0, (unsigned long long)(unsigned)cp0);
        wc[par][wid] = wpos;
      }
      __syncthreads();
      ulonglong2 e0 = wv[par][0];
      float4 q0 = wc[par][0];
      unsigned long long bv = e0.x;
      int bp = (int)e0.y;
      float fx = q0.x, fy = q0.y, fz = q0.z;
#pragma unroll
      for (int w = 1; w < 8; ++w) {
        ulonglong2 e = wv[par][w];
        float4 q = wc[par][w];
        bool t = (e.x > bv) || (e.x == bv && (int)e.y < bp);
        bv = t ? e.x : bv;
        bp = t ? (int)e.y : bp;
        fx = t ? q.x : fx;
        fy = t ? q.y : fy;
        fz = t ? q.z : fz;
      }
      sx = fx; sy = fy; sz = fz;
      if (tid == 0) fpspos[(size_t)b * FPSK + it] = (unsigned)bp;
    }
  } else {
    // --------------------------- fuse_off path ----------------------------
    const int fb = blockIdx.x - 4;  // 0..511
    double* sa = (double*)smem;
    double* sc = (double*)(smem + 2048);
    double(*w2)[3] = (double(*)[3])(smem + 4096);
    if (tid < 256) {
      sa[tid] = a_off[tid];
      sc[tid] = c_off[tid];
#pragma unroll
      for (int k = 0; k < 3; ++k) w2[tid][k] = (double)w_off2[tid * 3 + k];
    }
    __syncthreads();
    const int lane = tid & 63, wid = tid >> 6;
    const int gw = fb * 8 + wid;
    for (int r = gw; r < N; r += 4096) {
      double po0 = 0, po1 = 0, po2 = 0;
#pragma unroll
      for (int q = 0; q < 4; ++q) {
        int c = lane + 64 * q;
        double h = (double)Hoff[(size_t)r * 256 + c];
        double v = fma(h, sa[c], sc[c]);
        v = v > 0.0 ? v : 0.0;
        po0 = fma(v, w2[c][0], po0);
        po1 = fma(v, w2[c][1], po1);
        po2 = fma(v, w2[c][2], po2);
      }
#pragma unroll
      for (int off = 32; off; off >>= 1) {
        po0 += __shfl_xor(po0, off);
        po1 += __shfl_xor(po1, off);
        po2 += __shfl_xor(po2, off);
      }
      if (lane == 0) {
        float x = xyz[(size_t)r * 3], y = xyz[(size_t)r * 3 + 1], z = xyz[(size_t)r * 3 + 2];
        float bs = (float)(r >> 16);
        double offv[3] = {po0 + (double)b_off2[0], po1 + (double)b_off2[1], po2 + (double)b_off2[2]};
        const double rng[3] = {3.0, 3.0, 2.0};
        float pxyz[3] = {x, y, z};
        out_votes[(size_t)r * 4 + 0] = bs;
#pragma unroll
        for (int k = 0; k < 3; ++k) {
          double lim = offv[k];
          lim = lim < -rng[k] ? -rng[k] : lim;
          lim = lim > rng[k] ? rng[k] : lim;
          out_votes[(size_t)r * 4 + 1 + k] = (float)((double)pxyz[k] + lim);
        }
      }
    }
  }
}

// ---------------------------------------------------------------------------
// Final gather: fps_indices (as float), vote_candidates, vote_features.
// ---------------------------------------------------------------------------
__global__ __launch_bounds__(256) void k_gather(const unsigned int* __restrict__ topk,
                                                const unsigned int* __restrict__ fpspos,
                                                const float* __restrict__ feats,
                                                const float* __restrict__ votes_out,
                                                float* __restrict__ o0, float* __restrict__ o1,
                                                float* __restrict__ o5) {
  const int r = blockIdx.x;
  const int b = r / FPSK;
  __shared__ unsigned int gsh;
  if (threadIdx.x == 0) {
    unsigned pos = fpspos[r];
    unsigned local = topk[(size_t)b * TOPK + pos];
    gsh = (unsigned)(b * NB_V) + local;
  }
  __syncthreads();
  const unsigned g = gsh;
  o1[(size_t)r * 256 + threadIdx.x] = feats[(size_t)g * 256 + threadIdx.x];
  if (threadIdx.x < 4) o0[(size_t)r * 4 + threadIdx.x] = votes_out[(size_t)g * 4 + threadIdx.x];
  if (threadIdx.x == 4) o5[r] = (float)g;
}

// ---------------------------------------------------------------------------
extern "C" void kernel_launch(void* const* d_in, const int* in_sizes, int n_in,
                              void* d_out, int out_size, void* d_ws, size_t ws_size,
                              hipStream_t stream) {
  const float* xyz = (const float*)d_in[0];
  const float* feats = (const float*)d_in[1];
  const float* w_off1 = (const float*)d_in[2];
  const float* g_off1 = (const float*)d_in[3];
  const float* be_off1 = (const float*)d_in[4];
  const float* w_off2 = (const float*)d_in[5];
  const float* b_off2 = (const float*)d_in[6];
  const float* w_cls1 = (const float*)d_in[7];
  const float* g_cls1 = (const float*)d_in[8];
  const float* be_cls1 = (const float*)d_in[9];
  const float* w_cls2 = (const float*)d_in[10];
  const float* b_cls2 = (const float*)d_in[11];

  const int N = in_sizes[0] / 3;
  const int B = N / NB_V;
  const int BP = B * FPSK;

  float* out = (float*)d_out;
  float* o0 = out;                           // vote_candidates (BP,4)
  float* o1 = o0 + (size_t)BP * 4;           // vote_features   (BP,256)
  float* o2 = o1 + (size_t)BP * 256;         // seeds           (N,4)
  float* o3 = o2 + (size_t)N * 4;            // seed_cls        (N,3)
  float* o4 = o3 + (size_t)N * 3;            // votes           (N,4)
  float* o5 = o4 + (size_t)N * 4;            // fps_indices     (BP,)

  char* w = (char*)d_ws;
  float* Hoff = (float*)w;                           // N*1024 B
  float* Hcls = (float*)(w + (size_t)N * 1024);      // N*1024 B
  char* p0 = w + (size_t)N * 2048;
  double* part_cls = (double*)p0;                    // 16 MB
  float2* part_off = (float2*)(p0 + 16777216);       // 8 MB
  char* p1 = p0 + 16777216 + 8388608;
  double* a_cls = (double*)p1;
  double* c_cls = a_cls + 256;
  double* a_off = c_cls + 256;
  double* c_off = a_off + 256;
  unsigned long long* keys = (unsigned long long*)(p1 + 8192);   // N*8
  unsigned int* topkbuf = (unsigned int*)((char*)keys + (size_t)N * 8);
  unsigned int* fpspos = topkbuf + (size_t)B * TOPK;

  const int NCB = (N / 64) * 2;
  const int NGB = (N / 64) * 4;
  k_dualgemm<<<dim3(NCB + NGB), dim3(256), 0, stream>>>(feats, w_cls1, w_off1, Hcls, Hoff,
                                                        part_cls, part_off, N);
  k_fins<<<dim3(512), dim3(256), 0, stream>>>(part_cls, part_off, g_cls1, be_cls1,
                                              g_off1, be_off1, a_cls, c_cls, a_off, c_off, N);
  k_fuse_cls<<<dim3(1024), dim3(256), 0, stream>>>(Hcls, xyz, w_cls2, b_cls2, a_cls, c_cls,
                                                   o2, o3, keys, N);
  k_topk<<<dim3(B), dim3(1024), 0, stream>>>(keys, topkbuf);
  k_fused2<<<dim3(4 + 512), dim3(512), 0, stream>>>(xyz, topkbuf, fpspos, Hoff, a_off,
                                                    c_off, w_off2, b_off2, o4, N);
  k_gather<<<dim3(BP), dim3(256), 0, stream>>>(topkbuf, fpspos, feats, o4, o0, o1, o5);
}

// Round 14
// 3475.743 us; speedup vs baseline: 1.1956x; 1.1956x over previous
//
#include <hip/hip_runtime.h>

#define NB_V 65536
#define TOPK 4096
#define FPSK 2048

typedef short bf16x8 __attribute__((ext_vector_type(8)));
typedef float f32x4 __attribute__((ext_vector_type(4)));

// ---------------------------------------------------------------------------
// DUAL GEMM (validated R13): cls f64-accum GEMM (64x128, 4x8 acc, f64 LDS
// staging, W group-stride-10 swizzle) + offset bf16-MFMA GEMM; BN stats
// partials folded into both epilogues.
// ---------------------------------------------------------------------------
__global__ __launch_bounds__(256, 2) void k_dualgemm(
    const float* __restrict__ A, const float* __restrict__ Wcls,
    const float* __restrict__ Woff, float* __restrict__ Hcls,
    float* __restrict__ Hoff, double* __restrict__ part_cls,
    float2* __restrict__ part_off, int N) {
  __shared__ __align__(16) char smem[67584];
  const int tid = threadIdx.x;
  const int NCB = (N >> 6) << 1;   // (N/64)*2 cls blocks

  if ((int)blockIdx.x < NCB) {
    double(*Asm)[33] = (double(*)[33])smem;              // [64][33] f64
    double* BfF = (double*)(smem + 16896);               // [32][160] f64
    const int tx = tid & 15, ty = tid >> 4;
    const int cb = blockIdx.x & 1;
    const int rb = blockIdx.x >> 1;
    double acc[4][8];
#pragma unroll
    for (int i = 0; i < 4; ++i)
#pragma unroll
      for (int j = 0; j < 8; ++j) acc[i][j] = 0.0;

    for (int kc = 0; kc < 256; kc += 32) {
#pragma unroll
      for (int l = 0; l < 8; ++l) {
        int f = tid + 256 * l;
        int r = f >> 5, c = f & 31;
        Asm[r][c] = (double)A[(size_t)(rb * 64 + r) * 256 + kc + c];
      }
#pragma unroll
      for (int l = 0; l < 16; ++l) {
        int f = tid + 256 * l;
        int kr = f >> 7, c = f & 127;
        BfF[kr * 160 + (c >> 3) * 10 + (c & 7)] =
            (double)Wcls[(size_t)(kc + kr) * 256 + cb * 128 + c];
      }
      __syncthreads();
#pragma unroll 4
      for (int kk = 0; kk < 32; ++kk) {
        double a0[4];
#pragma unroll
        for (int i = 0; i < 4; ++i) a0[i] = Asm[ty + 16 * i][kk];
        const double* bR = BfF + kk * 160 + tx * 10;
        double2 b01 = *reinterpret_cast<const double2*>(bR);
        double2 b23 = *reinterpret_cast<const double2*>(bR + 2);
        double2 b45 = *reinterpret_cast<const double2*>(bR + 4);
        double2 b67 = *reinterpret_cast<const double2*>(bR + 6);
        double b0[8] = {b01.x, b01.y, b23.x, b23.y, b45.x, b45.y, b67.x, b67.y};
#pragma unroll
        for (int i = 0; i < 4; ++i)
#pragma unroll
          for (int j = 0; j < 8; ++j) acc[i][j] = fma(a0[i], b0[j], acc[i][j]);
      }
      __syncthreads();
    }
    double s[8], q[8];
#pragma unroll
    for (int j = 0; j < 8; ++j) { s[j] = 0.0; q[j] = 0.0; }
#pragma unroll
    for (int i = 0; i < 4; ++i) {
      float hv[8];
#pragma unroll
      for (int j = 0; j < 8; ++j) {
        hv[j] = (float)acc[i][j];
        double d = (double)hv[j];
        s[j] += d;
        q[j] = fma(d, d, q[j]);
      }
      size_t base = (size_t)(rb * 64 + ty + 16 * i) * 256 + cb * 128 + tx * 8;
      *reinterpret_cast<float4*>(&Hcls[base]) = make_float4(hv[0], hv[1], hv[2], hv[3]);
      *reinterpret_cast<float4*>(&Hcls[base + 4]) = make_float4(hv[4], hv[5], hv[6], hv[7]);
    }
    __syncthreads();  // reuse LDS
    double(*ps)[128] = (double(*)[128])smem;
    double(*pq)[128] = (double(*)[128])(smem + 16384);
#pragma unroll
    for (int j = 0; j < 8; ++j) {
      ps[ty][tx * 8 + j] = s[j];
      pq[ty][tx * 8 + j] = q[j];
    }
    __syncthreads();
    if (tid < 128) {
      double S = 0.0, Q = 0.0;
#pragma unroll
      for (int t = 0; t < 16; ++t) { S += ps[t][tid]; Q += pq[t][tid]; }
      part_cls[(size_t)blockIdx.x * 256 + tid * 2] = S;
      part_cls[(size_t)blockIdx.x * 256 + tid * 2 + 1] = Q;
    }
  } else {
    unsigned short(*As)[264] = (unsigned short(*)[264])smem;
    unsigned short(*Bs)[264] = (unsigned short(*)[264])(smem + 33792);
    const int gb = blockIdx.x - NCB;
    const int cb = gb & 3;
    const int rb = gb >> 2;
#pragma unroll
    for (int l = 0; l < 16; ++l) {
      int f = tid + 256 * l;
      int r = f >> 6, c4 = (f & 63) << 2;
      float4 v = *reinterpret_cast<const float4*>(&A[(size_t)(rb * 64 + r) * 256 + c4]);
      ushort4 u;
      u.x = (unsigned short)(__float_as_uint(v.x) >> 16);
      u.y = (unsigned short)(__float_as_uint(v.y) >> 16);
      u.z = (unsigned short)(__float_as_uint(v.z) >> 16);
      u.w = (unsigned short)(__float_as_uint(v.w) >> 16);
      *reinterpret_cast<ushort4*>(&As[r][c4]) = u;
    }
    {
      const int c = tid & 63;
      const int kg = tid >> 6;
#pragma unroll
      for (int j = 0; j < 16; ++j) {
        int k0 = kg * 64 + j * 4;
        ushort4 u;
        u.x = (unsigned short)(__float_as_uint(Woff[(size_t)(k0 + 0) * 256 + cb * 64 + c]) >> 16);
        u.y = (unsigned short)(__float_as_uint(Woff[(size_t)(k0 + 1) * 256 + cb * 64 + c]) >> 16);
        u.z = (unsigned short)(__float_as_uint(Woff[(size_t)(k0 + 2) * 256 + cb * 64 + c]) >> 16);
        u.w = (unsigned short)(__float_as_uint(Woff[(size_t)(k0 + 3) * 256 + cb * 64 + c]) >> 16);
        *reinterpret_cast<ushort4*>(&Bs[c][k0]) = u;
      }
    }
    __syncthreads();
    const int lane = tid & 63, w = tid >> 6;
    const int m = lane & 15, kq = lane >> 4;
    f32x4 acc[4];
#pragma unroll
    for (int s = 0; s < 4; ++s) acc[s] = (f32x4){0.f, 0.f, 0.f, 0.f};
#pragma unroll
    for (int k0 = 0; k0 < 256; k0 += 32) {
      bf16x8 a = *reinterpret_cast<const bf16x8*>(&As[w * 16 + m][k0 + kq * 8]);
#pragma unroll
      for (int s = 0; s < 4; ++s) {
        bf16x8 bfr = *reinterpret_cast<const bf16x8*>(&Bs[s * 16 + m][k0 + kq * 8]);
        acc[s] = __builtin_amdgcn_mfma_f32_16x16x32_bf16(a, bfr, acc[s], 0, 0, 0);
      }
    }
    double cs[4], cq[4];
#pragma unroll
    for (int s = 0; s < 4; ++s) { cs[s] = 0.0; cq[s] = 0.0; }
#pragma unroll
    for (int s = 0; s < 4; ++s)
#pragma unroll
      for (int i = 0; i < 4; ++i) {
        float hv = acc[s][i];
        Hoff[(size_t)(rb * 64 + w * 16 + kq * 4 + i) * 256 + cb * 64 + s * 16 + m] = hv;
        double d = (double)hv;
        cs[s] += d;
        cq[s] = fma(d, d, cq[s]);
      }
    __syncthreads();  // reuse LDS
    double(*ps)[64] = (double(*)[64])smem;
    double(*pq)[64] = (double(*)[64])(smem + 8192);
#pragma unroll
    for (int s = 0; s < 4; ++s) {
      ps[w * 4 + kq][s * 16 + m] = cs[s];
      pq[w * 4 + kq][s * 16 + m] = cq[s];
    }
    __syncthreads();
    if (tid < 64) {
      double S = 0.0, Q = 0.0;
#pragma unroll
      for (int t = 0; t < 16; ++t) { S += ps[t][tid]; Q += pq[t][tid]; }
      part_off[(size_t)gb * 64 + tid] = make_float2((float)S, (float)Q);
    }
  }
}

// ---------------------------------------------------------------------------
// Stats finalize, parallel (validated R12).
// ---------------------------------------------------------------------------
__global__ __launch_bounds__(256) void k_fins(const double* __restrict__ part_cls,
                                              const float2* __restrict__ part_off,
                                              const float* __restrict__ g_cls,
                                              const float* __restrict__ be_cls,
                                              const float* __restrict__ g_off,
                                              const float* __restrict__ be_off,
                                              double* __restrict__ a_cls,
                                              double* __restrict__ c_cls,
                                              double* __restrict__ a_off,
                                              double* __restrict__ c_off, int N) {
  __shared__ double ls[256], lq[256];
  const int tid = threadIdx.x;
  const int nrb = N >> 6;
  double S = 0.0, Q = 0.0;
  if ((int)blockIdx.x < 256) {
    const int c = blockIdx.x;
    const int cbb = c >> 7, cl = c & 127;
    for (int m = 0; m < nrb / 256; ++m) {
      int rb = tid + 256 * m;
      const double* p = part_cls + ((size_t)(rb * 2 + cbb) * 256 + cl * 2);
      S += p[0];
      Q += p[1];
    }
  } else {
    const int c = blockIdx.x - 256;
    const int ccb = c >> 6, cl = c & 63;
    for (int m = 0; m < nrb / 256; ++m) {
      int r2 = tid + 256 * m;
      float2 p = part_off[(size_t)(r2 * 4 + ccb) * 64 + cl];
      S += (double)p.x;
      Q += (double)p.y;
    }
  }
  ls[tid] = S;
  lq[tid] = Q;
  __syncthreads();
  for (int st = 128; st; st >>= 1) {
    if (tid < st) {
      ls[tid] += ls[tid + st];
      lq[tid] += lq[tid + st];
    }
    __syncthreads();
  }
  if (tid == 0) {
    double mean = ls[0] / (double)N;
    double var = lq[0] / (double)N - mean * mean;
    if ((int)blockIdx.x < 256) {
      const int c = blockIdx.x;
      double a = (double)g_cls[c] / sqrt(var + 1e-5);
      a_cls[c] = a;
      c_cls[c] = (double)be_cls[c] - mean * a;
    } else {
      const int c = blockIdx.x - 256;
      double a = (double)g_off[c] / sqrt(var + 1e-5);
      a_off[c] = a;
      c_off[c] = (double)be_off[c] - mean * a;
    }
  }
}

// ---------------------------------------------------------------------------
// cls-side fuse: BN+ReLU+layer2 on Hcls -> seeds, seed_cls, sort keys.
// ---------------------------------------------------------------------------
__global__ __launch_bounds__(256) void k_fuse_cls(const float* __restrict__ Hcls,
                                                  const float* __restrict__ xyz,
                                                  const float* __restrict__ w_cls2,
                                                  const float* __restrict__ b_cls2,
                                                  const double* __restrict__ aarr,
                                                  const double* __restrict__ carr,
                                                  float* __restrict__ out_seeds,
                                                  float* __restrict__ out_cls,
                                                  unsigned long long* __restrict__ keys,
                                                  int N) {
  __shared__ double sa[256], sc[256];
  __shared__ double w2[256][3];
  const int tid = threadIdx.x;
  {
    sa[tid] = aarr[tid];
    sc[tid] = carr[tid];
#pragma unroll
    for (int k = 0; k < 3; ++k) w2[tid][k] = (double)w_cls2[tid * 3 + k];
  }
  __syncthreads();
  const int lane = tid & 63, wid = tid >> 6;
  const int gw = blockIdx.x * 4 + wid;
  for (int r = gw; r < N; r += 4096) {
    double pc0 = 0, pc1 = 0, pc2 = 0;
#pragma unroll
    for (int q = 0; q < 4; ++q) {
      int c = lane + 64 * q;
      double h2 = (double)Hcls[(size_t)r * 256 + c];
      double v2 = fma(h2, sa[c], sc[c]);
      v2 = v2 > 0.0 ? v2 : 0.0;
      pc0 = fma(v2, w2[c][0], pc0);
      pc1 = fma(v2, w2[c][1], pc1);
      pc2 = fma(v2, w2[c][2], pc2);
    }
#pragma unroll
    for (int off = 32; off; off >>= 1) {
      pc0 += __shfl_xor(pc0, off);
      pc1 += __shfl_xor(pc1, off);
      pc2 += __shfl_xor(pc2, off);
    }
    if (lane == 0) {
      float x = xyz[(size_t)r * 3], y = xyz[(size_t)r * 3 + 1], z = xyz[(size_t)r * 3 + 2];
      float bs = (float)(r >> 16);
      out_seeds[(size_t)r * 4 + 0] = bs;
      out_seeds[(size_t)r * 4 + 1] = x;
      out_seeds[(size_t)r * 4 + 2] = y;
      out_seeds[(size_t)r * 4 + 3] = z;
      double c0 = pc0 + (double)b_cls2[0];
      double c1 = pc1 + (double)b_cls2[1];
      double c2v = pc2 + (double)b_cls2[2];
      out_cls[(size_t)r * 3 + 0] = (float)c0;
      out_cls[(size_t)r * 3 + 1] = (float)c1;
      out_cls[(size_t)r * 3 + 2] = (float)c2v;
      double s = c0 > c1 ? c0 : c1;
      s = s > c2v ? s : c2v;
      long long bits = __double_as_longlong(s);
      unsigned long long key =
          bits >= 0 ? ((unsigned long long)bits | 0x8000000000000000ull) : ~((unsigned long long)bits);
      keys[r] = key;
    }
  }
}

// ---------------------------------------------------------------------------
// Per-batch top-4096 radix select + bitonic sort (validated).
// ---------------------------------------------------------------------------
__global__ __launch_bounds__(1024) void k_topk(const unsigned long long* __restrict__ keys,
                                               unsigned int* __restrict__ topk) {
  const int b = blockIdx.x;
  const unsigned long long* K = keys + (size_t)b * NB_V;
  __shared__ unsigned int hist[256];
  __shared__ unsigned long long pfx_s;
  __shared__ int want_s;
  __shared__ unsigned long long skey[TOPK];
  __shared__ unsigned int sidx[TOPK];
  __shared__ int cnt_hi, cnt_eq;
  __shared__ unsigned int eq_idx[1024];
  const int tid = threadIdx.x;
  const int lane = tid & 63;
  if (tid == 0) { pfx_s = 0ull; want_s = TOPK; }
  __syncthreads();
  for (int p = 0; p < 8; ++p) {
    const int shift = 56 - 8 * p;
    if (tid < 256) hist[tid] = 0;
    __syncthreads();
    unsigned long long pfx = pfx_s;
    for (int i = tid; i < NB_V; i += 1024) {
      unsigned long long k = K[i];
      bool ok;
      if (p == 0) ok = true;
      else ok = ((k >> (shift + 8)) == (pfx >> (shift + 8)));
      unsigned bin = ok ? (unsigned)((k >> shift) & 255u) : 0xFFFFFFFFu;
      unsigned long long okm = __ballot(ok);
      if (okm) {
        int leader = __ffsll((unsigned long long)okm) - 1;
        unsigned pb = __shfl(bin, leader);
        unsigned long long m = __ballot(ok && bin == pb);
        if (lane == leader) atomicAdd(&hist[pb], (unsigned)__popcll(m));
        if (ok && bin != pb) atomicAdd(&hist[bin], 1u);
      }
    }
    __syncthreads();
    if (tid == 0) {
      int want = want_s;
      int cum = 0, d = 255;
      for (; d >= 0; --d) {
        int c = (int)hist[d];
        if (cum + c >= want) break;
        cum += c;
      }
      want_s = want - cum;
      pfx_s = pfx_s | ((unsigned long long)d << shift);
    }
    __syncthreads();
  }
  const unsigned long long Kthr = pfx_s;
  const int T = want_s;
  if (tid == 0) { cnt_hi = 0; cnt_eq = 0; }
  __syncthreads();
  for (int i = tid; i < NB_V; i += 1024) {
    unsigned long long k = K[i];
    if (k > Kthr) {
      int pos = atomicAdd(&cnt_hi, 1);
      skey[pos] = k;
      sidx[pos] = (unsigned)i;
    } else if (k == Kthr) {
      int pos = atomicAdd(&cnt_eq, 1);
      if (pos < 1024) eq_idx[pos] = (unsigned)i;
    }
  }
  __syncthreads();
  if (tid == 0) {
    int m = cnt_eq; if (m > 1024) m = 1024;
    for (int a2 = 1; a2 < m; ++a2) {
      unsigned v = eq_idx[a2];
      int b2 = a2 - 1;
      while (b2 >= 0 && eq_idx[b2] > v) { eq_idx[b2 + 1] = eq_idx[b2]; --b2; }
      eq_idx[b2 + 1] = v;
    }
    for (int t = 0; t < T; ++t) { skey[cnt_hi + t] = Kthr; sidx[cnt_hi + t] = eq_idx[t]; }
  }
  __syncthreads();
  for (int k2 = 2; k2 <= TOPK; k2 <<= 1) {
    for (int j = k2 >> 1; j > 0; j >>= 1) {
      for (int i = tid; i < TOPK; i += 1024) {
        int ix = i ^ j;
        if (ix > i) {
          unsigned long long ka = skey[i], kb = skey[ix];
          unsigned int ia = sidx[i], ib = sidx[ix];
          bool a_first = (ka > kb) || (ka == kb && ia < ib);
          bool up = (i & k2) == 0;
          if (up ? !a_first : a_first) {
            skey[i] = kb; skey[ix] = ka;
            sidx[i] = ib; sidx[ix] = ia;
          }
        }
      }
      __syncthreads();
    }
  }
  for (int i = tid; i < TOPK; i += 1024) topk[(size_t)b * TOPK + i] = sidx[i];
}

// ---------------------------------------------------------------------------
// FUSED2: blocks 0..3 = D-FPS (256 thr x 16 pts, 1 wave/SIMD — confirmed
// optimal shape R5/R13). NEW: coords in f64 NAMED registers (exact; drops 48
// cvt ops/iter). (256,1) -> VGPR budget 512, no spill. blocks 4..1027 =
// fuse_off (hidden in FPS window). 82944 B LDS -> 1 block/CU.
// ---------------------------------------------------------------------------
template <int CTRL>
__device__ __forceinline__ void dpp_merge2(unsigned long long& v, int& p) {
  unsigned lo = (unsigned)v, hi = (unsigned)(v >> 32);
  unsigned olo = (unsigned)__builtin_amdgcn_update_dpp(0, (int)lo, CTRL, 0xF, 0xF, false);
  unsigned ohi = (unsigned)__builtin_amdgcn_update_dpp(0, (int)hi, CTRL, 0xF, 0xF, false);
  int op = __builtin_amdgcn_update_dpp(0, p, CTRL, 0xF, 0xF, false);
  unsigned long long ov = ((unsigned long long)ohi << 32) | (unsigned long long)olo;
  bool t = (ov > v) || (ov == v && op < p);
  v = t ? ov : v;
  p = t ? op : p;
}

__device__ __forceinline__ void shfl_merge2(unsigned long long& v, int& p, int mask) {
  unsigned long long ov = __shfl_xor(v, mask);
  int op = __shfl_xor(p, mask);
  bool t = (ov > v) || (ov == v && op < p);
  v = t ? ov : v;
  p = t ? op : p;
}

#define FPS_REP16(M) M(0) M(1) M(2) M(3) M(4) M(5) M(6) M(7) \
                     M(8) M(9) M(10) M(11) M(12) M(13) M(14) M(15)

__global__ __launch_bounds__(256, 1) void k_fused2(const float* __restrict__ xyz,
                                                   const unsigned int* __restrict__ topk,
                                                   unsigned int* __restrict__ fpspos,
                                                   const float* __restrict__ Hoff,
                                                   const double* __restrict__ a_off,
                                                   const double* __restrict__ c_off,
                                                   const float* __restrict__ w_off2,
                                                   const float* __restrict__ b_off2,
                                                   float* __restrict__ out_votes, int N) {
  __shared__ __align__(16) char smem[82944];  // > 80 KB -> 1 block/CU
  const int tid = threadIdx.x;

  if (blockIdx.x < 4) {
    // ------------------------------ FPS path ------------------------------
    float4* cpos = (float4*)smem;  // 64 KB
    ulonglong2(*wv)[4] = (ulonglong2(*)[4])(smem + 65536);
    float4(*wc)[4] = (float4(*)[4])(smem + 65792);
    const int b = blockIdx.x;

#define FPS_DECL(J) double x##J, y##J, z##J, d##J;
    FPS_REP16(FPS_DECL)

#define FPS_INIT(J) { \
    int p = tid + 256 * (J); \
    unsigned idx = topk[(size_t)b * TOPK + p]; \
    size_t base = ((size_t)b * NB_V + idx) * 3; \
    float fx = xyz[base], fy = xyz[base + 1], fz = xyz[base + 2]; \
    x##J = (double)fx; y##J = (double)fy; z##J = (double)fz; \
    d##J = 1e10; \
    cpos[p] = make_float4(fx, fy, fz, 0.0f); }
    FPS_REP16(FPS_INIT)

    if (tid == 0) {
      wc[0][0] = make_float4((float)x0, (float)y0, (float)z0, 0.0f);
      fpspos[(size_t)b * FPSK] = 0u;
    }
    __syncthreads();
    float4 s0 = wc[0][0];
    float sx = s0.x, sy = s0.y, sz = s0.z;
    const int lane = tid & 63, wid = tid >> 6;

    for (int it = 1; it < FPSK; ++it) {
      const int par = it & 1;
      double lx = (double)sx, ly = (double)sy, lz = (double)sz;
      unsigned long long cv0, cv1;
      int cp0, cp1;
#define FPS_UPD(J) { \
    double dx = x##J - lx; \
    double dy = y##J - ly; \
    double dz = z##J - lz; \
    double dd = __dadd_rn(__dadd_rn(__dmul_rn(dx, dx), __dmul_rn(dy, dy)), __dmul_rn(dz, dz)); \
    d##J = fmin(d##J, dd); \
    unsigned long long db = (unsigned long long)__double_as_longlong(d##J); \
    if ((J) == 0) { cv0 = db; cp0 = tid; } \
    else if ((J) == 1) { cv1 = db; cp1 = tid + 256; } \
    else if (((J) & 1) == 0) { bool g = db > cv0; cv0 = g ? db : cv0; cp0 = g ? (tid + 256 * (J)) : cp0; } \
    else { bool g = db > cv1; cv1 = g ? db : cv1; cp1 = g ? (tid + 256 * (J)) : cp1; } }
      FPS_REP16(FPS_UPD)
      {  // merge odd chain into even (tie -> min pos)
        bool g = (cv1 > cv0) || (cv1 == cv0 && cp1 < cp0);
        cv0 = g ? cv1 : cv0;
        cp0 = g ? cp1 : cp0;
      }
      dpp_merge2<0xB1>(cv0, cp0);   // quad_perm xor1
      dpp_merge2<0x4E>(cv0, cp0);   // quad_perm xor2
      dpp_merge2<0x124>(cv0, cp0);  // row_ror:4
      dpp_merge2<0x128>(cv0, cp0);  // row_ror:8 -> row winner in all 16 lanes
      shfl_merge2(cv0, cp0, 16);
      shfl_merge2(cv0, cp0, 32);    // wave winner in all 64 lanes
      float4 wpos = cpos[cp0];      // uniform addr -> broadcast ds_read_b128
      if (lane == 0) {
        wv[par][wid] = make_ulonglong2(cv0, (unsigned long long)(unsigned)cp0);
        wc[par][wid] = wpos;
      }
      __syncthreads();
      ulonglong2 e0 = wv[par][0];
      float4 q0 = wc[par][0];
      unsigned long long bv = e0.x;
      int bp = (int)e0.y;
      float fx = q0.x, fy = q0.y, fz = q0.z;
#pragma unroll
      for (int w = 1; w < 4; ++w) {
        ulonglong2 e = wv[par][w];
        float4 q = wc[par][w];
        bool t = (e.x > bv) || (e.x == bv && (int)e.y < bp);
        bv = t ? e.x : bv;
        bp = t ? (int)e.y : bp;
        fx = t ? q.x : fx;
        fy = t ? q.y : fy;
        fz = t ? q.z : fz;
      }
      sx = fx; sy = fy; sz = fz;
      if (tid == 0) fpspos[(size_t)b * FPSK + it] = (unsigned)bp;
    }
  } else {
    // --------------------------- fuse_off path ----------------------------
    const int fb = blockIdx.x - 4;  // 0..1023
    double* sa = (double*)smem;
    double* sc = (double*)(smem + 2048);
    double(*w2)[3] = (double(*)[3])(smem + 4096);
    {
      sa[tid] = a_off[tid];
      sc[tid] = c_off[tid];
#pragma unroll
      for (int k = 0; k < 3; ++k) w2[tid][k] = (double)w_off2[tid * 3 + k];
    }
    __syncthreads();
    const int lane = tid & 63, wid = tid >> 6;
    const int gw = fb * 4 + wid;
    for (int r = gw; r < N; r += 4096) {
      double po0 = 0, po1 = 0, po2 = 0;
#pragma unroll
      for (int q = 0; q < 4; ++q) {
        int c = lane + 64 * q;
        double h = (double)Hoff[(size_t)r * 256 + c];
        double v = fma(h, sa[c], sc[c]);
        v = v > 0.0 ? v : 0.0;
        po0 = fma(v, w2[c][0], po0);
        po1 = fma(v, w2[c][1], po1);
        po2 = fma(v, w2[c][2], po2);
      }
#pragma unroll
      for (int off = 32; off; off >>= 1) {
        po0 += __shfl_xor(po0, off);
        po1 += __shfl_xor(po1, off);
        po2 += __shfl_xor(po2, off);
      }
      if (lane == 0) {
        float x = xyz[(size_t)r * 3], y = xyz[(size_t)r * 3 + 1], z = xyz[(size_t)r * 3 + 2];
        float bs = (float)(r >> 16);
        double offv[3] = {po0 + (double)b_off2[0], po1 + (double)b_off2[1], po2 + (double)b_off2[2]};
        const double rng[3] = {3.0, 3.0, 2.0};
        float pxyz[3] = {x, y, z};
        out_votes[(size_t)r * 4 + 0] = bs;
#pragma unroll
        for (int k = 0; k < 3; ++k) {
          double lim = offv[k];
          lim = lim < -rng[k] ? -rng[k] : lim;
          lim = lim > rng[k] ? rng[k] : lim;
          out_votes[(size_t)r * 4 + 1 + k] = (float)((double)pxyz[k] + lim);
        }
      }
    }
  }
}

// ---------------------------------------------------------------------------
// Final gather: fps_indices (as float), vote_candidates, vote_features.
// ---------------------------------------------------------------------------
__global__ __launch_bounds__(256) void k_gather(const unsigned int* __restrict__ topk,
                                                const unsigned int* __restrict__ fpspos,
                                                const float* __restrict__ feats,
                                                const float* __restrict__ votes_out,
                                                float* __restrict__ o0, float* __restrict__ o1,
                                                float* __restrict__ o5) {
  const int r = blockIdx.x;
  const int b = r / FPSK;
  __shared__ unsigned int gsh;
  if (threadIdx.x == 0) {
    unsigned pos = fpspos[r];
    unsigned local = topk[(size_t)b * TOPK + pos];
    gsh = (unsigned)(b * NB_V) + local;
  }
  __syncthreads();
  const unsigned g = gsh;
  o1[(size_t)r * 256 + threadIdx.x] = feats[(size_t)g * 256 + threadIdx.x];
  if (threadIdx.x < 4) o0[(size_t)r * 4 + threadIdx.x] = votes_out[(size_t)g * 4 + threadIdx.x];
  if (threadIdx.x == 4) o5[r] = (float)g;
}

// ---------------------------------------------------------------------------
extern "C" void kernel_launch(void* const* d_in, const int* in_sizes, int n_in,
                              void* d_out, int out_size, void* d_ws, size_t ws_size,
                              hipStream_t stream) {
  const float* xyz = (const float*)d_in[0];
  const float* feats = (const float*)d_in[1];
  const float* w_off1 = (const float*)d_in[2];
  const float* g_off1 = (const float*)d_in[3];
  const float* be_off1 = (const float*)d_in[4];
  const float* w_off2 = (const float*)d_in[5];
  const float* b_off2 = (const float*)d_in[6];
  const float* w_cls1 = (const float*)d_in[7];
  const float* g_cls1 = (const float*)d_in[8];
  const float* be_cls1 = (const float*)d_in[9];
  const float* w_cls2 = (const float*)d_in[10];
  const float* b_cls2 = (const float*)d_in[11];

  const int N = in_sizes[0] / 3;
  const int B = N / NB_V;
  const int BP = B * FPSK;

  float* out = (float*)d_out;
  float* o0 = out;                           // vote_candidates (BP,4)
  float* o1 = o0 + (size_t)BP * 4;           // vote_features   (BP,256)
  float* o2 = o1 + (size_t)BP * 256;         // seeds           (N,4)
  float* o3 = o2 + (size_t)N * 4;            // seed_cls        (N,3)
  float* o4 = o3 + (size_t)N * 3;            // votes           (N,4)
  float* o5 = o4 + (size_t)N * 4;            // fps_indices     (BP,)

  char* w = (char*)d_ws;
  float* Hoff = (float*)w;                           // N*1024 B
  float* Hcls = (float*)(w + (size_t)N * 1024);      // N*1024 B
  char* p0 = w + (size_t)N * 2048;
  double* part_cls = (double*)p0;                    // 16 MB
  float2* part_off = (float2*)(p0 + 16777216);       // 8 MB
  char* p1 = p0 + 16777216 + 8388608;
  double* a_cls = (double*)p1;
  double* c_cls = a_cls + 256;
  double* a_off = c_cls + 256;
  double* c_off = a_off + 256;
  unsigned long long* keys = (unsigned long long*)(p1 + 8192);   // N*8
  unsigned int* topkbuf = (unsigned int*)((char*)keys + (size_t)N * 8);
  unsigned int* fpspos = topkbuf + (size_t)B * TOPK;

  const int NCB = (N / 64) * 2;
  const int NGB = (N / 64) * 4;
  k_dualgemm<<<dim3(NCB + NGB), dim3(256), 0, stream>>>(feats, w_cls1, w_off1, Hcls, Hoff,
                                                        part_cls, part_off, N);
  k_fins<<<dim3(512), dim3(256), 0, stream>>>(part_cls, part_off, g_cls1, be_cls1,
                                              g_off1, be_off1, a_cls, c_cls, a_off, c_off, N);
  k_fuse_cls<<<dim3(1024), dim3(256), 0, stream>>>(Hcls, xyz, w_cls2, b_cls2, a_cls, c_cls,
                                                   o2, o3, keys, N);
  k_topk<<<dim3(B), dim3(1024), 0, stream>>>(keys, topkbuf);
  k_fused2<<<dim3(4 + 1024), dim3(256), 0, stream>>>(xyz, topkbuf, fpspos, Hoff, a_off,
                                                     c_off, w_off2, b_off2, o4, N);
  k_gather<<<dim3(BP), dim3(256), 0, stream>>>(topkbuf, fpspos, feats, o4, o0, o1, o5);
}

// Round 15
// 3445.333 us; speedup vs baseline: 1.2062x; 1.0088x over previous
//
#include <hip/hip_runtime.h>

#define NB_V 65536
#define TOPK 4096
#define FPSK 2048

typedef short bf16x8 __attribute__((ext_vector_type(8)));
typedef float f32x4 __attribute__((ext_vector_type(4)));
typedef unsigned int u32x2 __attribute__((ext_vector_type(2)));

// ---------------------------------------------------------------------------
// DUAL GEMM (validated R13/R14): cls f64-accum GEMM (64x128, 4x8 acc, f64 LDS
// staging, W group-stride-10 swizzle) + offset bf16-MFMA GEMM; BN stats
// partials folded into both epilogues.
// ---------------------------------------------------------------------------
__global__ __launch_bounds__(256, 2) void k_dualgemm(
    const float* __restrict__ A, const float* __restrict__ Wcls,
    const float* __restrict__ Woff, float* __restrict__ Hcls,
    float* __restrict__ Hoff, double* __restrict__ part_cls,
    float2* __restrict__ part_off, int N) {
  __shared__ __align__(16) char smem[67584];
  const int tid = threadIdx.x;
  const int NCB = (N >> 6) << 1;   // (N/64)*2 cls blocks

  if ((int)blockIdx.x < NCB) {
    double(*Asm)[33] = (double(*)[33])smem;              // [64][33] f64
    double* BfF = (double*)(smem + 16896);               // [32][160] f64
    const int tx = tid & 15, ty = tid >> 4;
    const int cb = blockIdx.x & 1;
    const int rb = blockIdx.x >> 1;
    double acc[4][8];
#pragma unroll
    for (int i = 0; i < 4; ++i)
#pragma unroll
      for (int j = 0; j < 8; ++j) acc[i][j] = 0.0;

    for (int kc = 0; kc < 256; kc += 32) {
#pragma unroll
      for (int l = 0; l < 8; ++l) {
        int f = tid + 256 * l;
        int r = f >> 5, c = f & 31;
        Asm[r][c] = (double)A[(size_t)(rb * 64 + r) * 256 + kc + c];
      }
#pragma unroll
      for (int l = 0; l < 16; ++l) {
        int f = tid + 256 * l;
        int kr = f >> 7, c = f & 127;
        BfF[kr * 160 + (c >> 3) * 10 + (c & 7)] =
            (double)Wcls[(size_t)(kc + kr) * 256 + cb * 128 + c];
      }
      __syncthreads();
#pragma unroll 4
      for (int kk = 0; kk < 32; ++kk) {
        double a0[4];
#pragma unroll
        for (int i = 0; i < 4; ++i) a0[i] = Asm[ty + 16 * i][kk];
        const double* bR = BfF + kk * 160 + tx * 10;
        double2 b01 = *reinterpret_cast<const double2*>(bR);
        double2 b23 = *reinterpret_cast<const double2*>(bR + 2);
        double2 b45 = *reinterpret_cast<const double2*>(bR + 4);
        double2 b67 = *reinterpret_cast<const double2*>(bR + 6);
        double b0[8] = {b01.x, b01.y, b23.x, b23.y, b45.x, b45.y, b67.x, b67.y};
#pragma unroll
        for (int i = 0; i < 4; ++i)
#pragma unroll
          for (int j = 0; j < 8; ++j) acc[i][j] = fma(a0[i], b0[j], acc[i][j]);
      }
      __syncthreads();
    }
    double s[8], q[8];
#pragma unroll
    for (int j = 0; j < 8; ++j) { s[j] = 0.0; q[j] = 0.0; }
#pragma unroll
    for (int i = 0; i < 4; ++i) {
      float hv[8];
#pragma unroll
      for (int j = 0; j < 8; ++j) {
        hv[j] = (float)acc[i][j];
        double d = (double)hv[j];
        s[j] += d;
        q[j] = fma(d, d, q[j]);
      }
      size_t base = (size_t)(rb * 64 + ty + 16 * i) * 256 + cb * 128 + tx * 8;
      *reinterpret_cast<float4*>(&Hcls[base]) = make_float4(hv[0], hv[1], hv[2], hv[3]);
      *reinterpret_cast<float4*>(&Hcls[base + 4]) = make_float4(hv[4], hv[5], hv[6], hv[7]);
    }
    __syncthreads();  // reuse LDS
    double(*ps)[128] = (double(*)[128])smem;
    double(*pq)[128] = (double(*)[128])(smem + 16384);
#pragma unroll
    for (int j = 0; j < 8; ++j) {
      ps[ty][tx * 8 + j] = s[j];
      pq[ty][tx * 8 + j] = q[j];
    }
    __syncthreads();
    if (tid < 128) {
      double S = 0.0, Q = 0.0;
#pragma unroll
      for (int t = 0; t < 16; ++t) { S += ps[t][tid]; Q += pq[t][tid]; }
      part_cls[(size_t)blockIdx.x * 256 + tid * 2] = S;
      part_cls[(size_t)blockIdx.x * 256 + tid * 2 + 1] = Q;
    }
  } else {
    unsigned short(*As)[264] = (unsigned short(*)[264])smem;
    unsigned short(*Bs)[264] = (unsigned short(*)[264])(smem + 33792);
    const int gb = blockIdx.x - NCB;
    const int cb = gb & 3;
    const int rb = gb >> 2;
#pragma unroll
    for (int l = 0; l < 16; ++l) {
      int f = tid + 256 * l;
      int r = f >> 6, c4 = (f & 63) << 2;
      float4 v = *reinterpret_cast<const float4*>(&A[(size_t)(rb * 64 + r) * 256 + c4]);
      ushort4 u;
      u.x = (unsigned short)(__float_as_uint(v.x) >> 16);
      u.y = (unsigned short)(__float_as_uint(v.y) >> 16);
      u.z = (unsigned short)(__float_as_uint(v.z) >> 16);
      u.w = (unsigned short)(__float_as_uint(v.w) >> 16);
      *reinterpret_cast<ushort4*>(&As[r][c4]) = u;
    }
    {
      const int c = tid & 63;
      const int kg = tid >> 6;
#pragma unroll
      for (int j = 0; j < 16; ++j) {
        int k0 = kg * 64 + j * 4;
        ushort4 u;
        u.x = (unsigned short)(__float_as_uint(Woff[(size_t)(k0 + 0) * 256 + cb * 64 + c]) >> 16);
        u.y = (unsigned short)(__float_as_uint(Woff[(size_t)(k0 + 1) * 256 + cb * 64 + c]) >> 16);
        u.z = (unsigned short)(__float_as_uint(Woff[(size_t)(k0 + 2) * 256 + cb * 64 + c]) >> 16);
        u.w = (unsigned short)(__float_as_uint(Woff[(size_t)(k0 + 3) * 256 + cb * 64 + c]) >> 16);
        *reinterpret_cast<ushort4*>(&Bs[c][k0]) = u;
      }
    }
    __syncthreads();
    const int lane = tid & 63, w = tid >> 6;
    const int m = lane & 15, kq = lane >> 4;
    f32x4 acc[4];
#pragma unroll
    for (int s = 0; s < 4; ++s) acc[s] = (f32x4){0.f, 0.f, 0.f, 0.f};
#pragma unroll
    for (int k0 = 0; k0 < 256; k0 += 32) {
      bf16x8 a = *reinterpret_cast<const bf16x8*>(&As[w * 16 + m][k0 + kq * 8]);
#pragma unroll
      for (int s = 0; s < 4; ++s) {
        bf16x8 bfr = *reinterpret_cast<const bf16x8*>(&Bs[s * 16 + m][k0 + kq * 8]);
        acc[s] = __builtin_amdgcn_mfma_f32_16x16x32_bf16(a, bfr, acc[s], 0, 0, 0);
      }
    }
    double cs[4], cq[4];
#pragma unroll
    for (int s = 0; s < 4; ++s) { cs[s] = 0.0; cq[s] = 0.0; }
#pragma unroll
    for (int s = 0; s < 4; ++s)
#pragma unroll
      for (int i = 0; i < 4; ++i) {
        float hv = acc[s][i];
        Hoff[(size_t)(rb * 64 + w * 16 + kq * 4 + i) * 256 + cb * 64 + s * 16 + m] = hv;
        double d = (double)hv;
        cs[s] += d;
        cq[s] = fma(d, d, cq[s]);
      }
    __syncthreads();  // reuse LDS
    double(*ps)[64] = (double(*)[64])smem;
    double(*pq)[64] = (double(*)[64])(smem + 8192);
#pragma unroll
    for (int s = 0; s < 4; ++s) {
      ps[w * 4 + kq][s * 16 + m] = cs[s];
      pq[w * 4 + kq][s * 16 + m] = cq[s];
    }
    __syncthreads();
    if (tid < 64) {
      double S = 0.0, Q = 0.0;
#pragma unroll
      for (int t = 0; t < 16; ++t) { S += ps[t][tid]; Q += pq[t][tid]; }
      part_off[(size_t)gb * 64 + tid] = make_float2((float)S, (float)Q);
    }
  }
}

// ---------------------------------------------------------------------------
// Stats finalize, parallel (validated R12).
// ---------------------------------------------------------------------------
__global__ __launch_bounds__(256) void k_fins(const double* __restrict__ part_cls,
                                              const float2* __restrict__ part_off,
                                              const float* __restrict__ g_cls,
                                              const float* __restrict__ be_cls,
                                              const float* __restrict__ g_off,
                                              const float* __restrict__ be_off,
                                              double* __restrict__ a_cls,
                                              double* __restrict__ c_cls,
                                              double* __restrict__ a_off,
                                              double* __restrict__ c_off, int N) {
  __shared__ double ls[256], lq[256];
  const int tid = threadIdx.x;
  const int nrb = N >> 6;
  double S = 0.0, Q = 0.0;
  if ((int)blockIdx.x < 256) {
    const int c = blockIdx.x;
    const int cbb = c >> 7, cl = c & 127;
    for (int m = 0; m < nrb / 256; ++m) {
      int rb = tid + 256 * m;
      const double* p = part_cls + ((size_t)(rb * 2 + cbb) * 256 + cl * 2);
      S += p[0];
      Q += p[1];
    }
  } else {
    const int c = blockIdx.x - 256;
    const int ccb = c >> 6, cl = c & 63;
    for (int m = 0; m < nrb / 256; ++m) {
      int r2 = tid + 256 * m;
      float2 p = part_off[(size_t)(r2 * 4 + ccb) * 64 + cl];
      S += (double)p.x;
      Q += (double)p.y;
    }
  }
  ls[tid] = S;
  lq[tid] = Q;
  __syncthreads();
  for (int st = 128; st; st >>= 1) {
    if (tid < st) {
      ls[tid] += ls[tid + st];
      lq[tid] += lq[tid + st];
    }
    __syncthreads();
  }
  if (tid == 0) {
    double mean = ls[0] / (double)N;
    double var = lq[0] / (double)N - mean * mean;
    if ((int)blockIdx.x < 256) {
      const int c = blockIdx.x;
      double a = (double)g_cls[c] / sqrt(var + 1e-5);
      a_cls[c] = a;
      c_cls[c] = (double)be_cls[c] - mean * a;
    } else {
      const int c = blockIdx.x - 256;
      double a = (double)g_off[c] / sqrt(var + 1e-5);
      a_off[c] = a;
      c_off[c] = (double)be_off[c] - mean * a;
    }
  }
}

// ---------------------------------------------------------------------------
// cls-side fuse: BN+ReLU+layer2 on Hcls -> seeds, seed_cls, sort keys.
// ---------------------------------------------------------------------------
__global__ __launch_bounds__(256) void k_fuse_cls(const float* __restrict__ Hcls,
                                                  const float* __restrict__ xyz,
                                                  const float* __restrict__ w_cls2,
                                                  const float* __restrict__ b_cls2,
                                                  const double* __restrict__ aarr,
                                                  const double* __restrict__ carr,
                                                  float* __restrict__ out_seeds,
                                                  float* __restrict__ out_cls,
                                                  unsigned long long* __restrict__ keys,
                                                  int N) {
  __shared__ double sa[256], sc[256];
  __shared__ double w2[256][3];
  const int tid = threadIdx.x;
  {
    sa[tid] = aarr[tid];
    sc[tid] = carr[tid];
#pragma unroll
    for (int k = 0; k < 3; ++k) w2[tid][k] = (double)w_cls2[tid * 3 + k];
  }
  __syncthreads();
  const int lane = tid & 63, wid = tid >> 6;
  const int gw = blockIdx.x * 4 + wid;
  for (int r = gw; r < N; r += 4096) {
    double pc0 = 0, pc1 = 0, pc2 = 0;
#pragma unroll
    for (int q = 0; q < 4; ++q) {
      int c = lane + 64 * q;
      double h2 = (double)Hcls[(size_t)r * 256 + c];
      double v2 = fma(h2, sa[c], sc[c]);
      v2 = v2 > 0.0 ? v2 : 0.0;
      pc0 = fma(v2, w2[c][0], pc0);
      pc1 = fma(v2, w2[c][1], pc1);
      pc2 = fma(v2, w2[c][2], pc2);
    }
#pragma unroll
    for (int off = 32; off; off >>= 1) {
      pc0 += __shfl_xor(pc0, off);
      pc1 += __shfl_xor(pc1, off);
      pc2 += __shfl_xor(pc2, off);
    }
    if (lane == 0) {
      float x = xyz[(size_t)r * 3], y = xyz[(size_t)r * 3 + 1], z = xyz[(size_t)r * 3 + 2];
      float bs = (float)(r >> 16);
      out_seeds[(size_t)r * 4 + 0] = bs;
      out_seeds[(size_t)r * 4 + 1] = x;
      out_seeds[(size_t)r * 4 + 2] = y;
      out_seeds[(size_t)r * 4 + 3] = z;
      double c0 = pc0 + (double)b_cls2[0];
      double c1 = pc1 + (double)b_cls2[1];
      double c2v = pc2 + (double)b_cls2[2];
      out_cls[(size_t)r * 3 + 0] = (float)c0;
      out_cls[(size_t)r * 3 + 1] = (float)c1;
      out_cls[(size_t)r * 3 + 2] = (float)c2v;
      double s = c0 > c1 ? c0 : c1;
      s = s > c2v ? s : c2v;
      long long bits = __double_as_longlong(s);
      unsigned long long key =
          bits >= 0 ? ((unsigned long long)bits | 0x8000000000000000ull) : ~((unsigned long long)bits);
      keys[r] = key;
    }
  }
}

// ---------------------------------------------------------------------------
// Per-batch top-4096 radix select + bitonic sort (validated).
// ---------------------------------------------------------------------------
__global__ __launch_bounds__(1024) void k_topk(const unsigned long long* __restrict__ keys,
                                               unsigned int* __restrict__ topk) {
  const int b = blockIdx.x;
  const unsigned long long* K = keys + (size_t)b * NB_V;
  __shared__ unsigned int hist[256];
  __shared__ unsigned long long pfx_s;
  __shared__ int want_s;
  __shared__ unsigned long long skey[TOPK];
  __shared__ unsigned int sidx[TOPK];
  __shared__ int cnt_hi, cnt_eq;
  __shared__ unsigned int eq_idx[1024];
  const int tid = threadIdx.x;
  const int lane = tid & 63;
  if (tid == 0) { pfx_s = 0ull; want_s = TOPK; }
  __syncthreads();
  for (int p = 0; p < 8; ++p) {
    const int shift = 56 - 8 * p;
    if (tid < 256) hist[tid] = 0;
    __syncthreads();
    unsigned long long pfx = pfx_s;
    for (int i = tid; i < NB_V; i += 1024) {
      unsigned long long k = K[i];
      bool ok;
      if (p == 0) ok = true;
      else ok = ((k >> (shift + 8)) == (pfx >> (shift + 8)));
      unsigned bin = ok ? (unsigned)((k >> shift) & 255u) : 0xFFFFFFFFu;
      unsigned long long okm = __ballot(ok);
      if (okm) {
        int leader = __ffsll((unsigned long long)okm) - 1;
        unsigned pb = __shfl(bin, leader);
        unsigned long long m = __ballot(ok && bin == pb);
        if (lane == leader) atomicAdd(&hist[pb], (unsigned)__popcll(m));
        if (ok && bin != pb) atomicAdd(&hist[bin], 1u);
      }
    }
    __syncthreads();
    if (tid == 0) {
      int want = want_s;
      int cum = 0, d = 255;
      for (; d >= 0; --d) {
        int c = (int)hist[d];
        if (cum + c >= want) break;
        cum += c;
      }
      want_s = want - cum;
      pfx_s = pfx_s | ((unsigned long long)d << shift);
    }
    __syncthreads();
  }
  const unsigned long long Kthr = pfx_s;
  const int T = want_s;
  if (tid == 0) { cnt_hi = 0; cnt_eq = 0; }
  __syncthreads();
  for (int i = tid; i < NB_V; i += 1024) {
    unsigned long long k = K[i];
    if (k > Kthr) {
      int pos = atomicAdd(&cnt_hi, 1);
      skey[pos] = k;
      sidx[pos] = (unsigned)i;
    } else if (k == Kthr) {
      int pos = atomicAdd(&cnt_eq, 1);
      if (pos < 1024) eq_idx[pos] = (unsigned)i;
    }
  }
  __syncthreads();
  if (tid == 0) {
    int m = cnt_eq; if (m > 1024) m = 1024;
    for (int a2 = 1; a2 < m; ++a2) {
      unsigned v = eq_idx[a2];
      int b2 = a2 - 1;
      while (b2 >= 0 && eq_idx[b2] > v) { eq_idx[b2 + 1] = eq_idx[b2]; --b2; }
      eq_idx[b2 + 1] = v;
    }
    for (int t = 0; t < T; ++t) { skey[cnt_hi + t] = Kthr; sidx[cnt_hi + t] = eq_idx[t]; }
  }
  __syncthreads();
  for (int k2 = 2; k2 <= TOPK; k2 <<= 1) {
    for (int j = k2 >> 1; j > 0; j >>= 1) {
      for (int i = tid; i < TOPK; i += 1024) {
        int ix = i ^ j;
        if (ix > i) {
          unsigned long long ka = skey[i], kb = skey[ix];
          unsigned int ia = sidx[i], ib = sidx[ix];
          bool a_first = (ka > kb) || (ka == kb && ia < ib);
          bool up = (i & k2) == 0;
          if (up ? !a_first : a_first) {
            skey[i] = kb; skey[ix] = ka;
            sidx[i] = ib; sidx[ix] = ia;
          }
        }
      }
      __syncthreads();
    }
  }
  for (int i = tid; i < TOPK; i += 1024) topk[(size_t)b * TOPK + i] = sidx[i];
}

// ---------------------------------------------------------------------------
// FUSED2: blocks 0..3 = D-FPS (256 thr x 16 pts, 1 wave/SIMD). NEW: the
// xor16/xor32 reduce levels use gfx950 v_permlane16/32_swap_b32 (pure VALU)
// instead of ds_bpermute shuffles — removes ~6 LDS round trips per iter from
// the dependent tail. Merge semantics identical (max val, tie -> min pos).
// blocks 4..1027 = fuse_off. 82944 B LDS -> 1 block/CU.
// ---------------------------------------------------------------------------
template <int CTRL>
__device__ __forceinline__ void dpp_merge2(unsigned long long& v, int& p) {
  unsigned lo = (unsigned)v, hi = (unsigned)(v >> 32);
  unsigned olo = (unsigned)__builtin_amdgcn_update_dpp(0, (int)lo, CTRL, 0xF, 0xF, false);
  unsigned ohi = (unsigned)__builtin_amdgcn_update_dpp(0, (int)hi, CTRL, 0xF, 0xF, false);
  int op = __builtin_amdgcn_update_dpp(0, p, CTRL, 0xF, 0xF, false);
  unsigned long long ov = ((unsigned long long)ohi << 32) | (unsigned long long)olo;
  bool t = (ov > v) || (ov == v && op < p);
  v = t ? ov : v;
  p = t ? op : p;
}

// v[lane^16] via permlane16_swap(v,v): d'=[r0,r0,r2,r2], s'=[r1,r1,r3,r3];
// pick d' on odd 16-rows, s' on even. Same scheme for lane^32 with 32_swap.
__device__ __forceinline__ unsigned pl16x(unsigned v, bool hi16) {
  u32x2 r = __builtin_amdgcn_permlane16_swap(v, v, false, false);
  return hi16 ? r.x : r.y;
}
__device__ __forceinline__ unsigned pl32x(unsigned v, bool hi32) {
  u32x2 r = __builtin_amdgcn_permlane32_swap(v, v, false, false);
  return hi32 ? r.x : r.y;
}

__device__ __forceinline__ void pl16_merge(unsigned long long& v, int& p, bool hi16) {
  unsigned olo = pl16x((unsigned)v, hi16);
  unsigned ohi = pl16x((unsigned)(v >> 32), hi16);
  int op = (int)pl16x((unsigned)p, hi16);
  unsigned long long ov = ((unsigned long long)ohi << 32) | (unsigned long long)olo;
  bool t = (ov > v) || (ov == v && op < p);
  v = t ? ov : v;
  p = t ? op : p;
}
__device__ __forceinline__ void pl32_merge(unsigned long long& v, int& p, bool hi32) {
  unsigned olo = pl32x((unsigned)v, hi32);
  unsigned ohi = pl32x((unsigned)(v >> 32), hi32);
  int op = (int)pl32x((unsigned)p, hi32);
  unsigned long long ov = ((unsigned long long)ohi << 32) | (unsigned long long)olo;
  bool t = (ov > v) || (ov == v && op < p);
  v = t ? ov : v;
  p = t ? op : p;
}

#define FPS_REP16(M) M(0) M(1) M(2) M(3) M(4) M(5) M(6) M(7) \
                     M(8) M(9) M(10) M(11) M(12) M(13) M(14) M(15)

__global__ __launch_bounds__(256, 1) void k_fused2(const float* __restrict__ xyz,
                                                   const unsigned int* __restrict__ topk,
                                                   unsigned int* __restrict__ fpspos,
                                                   const float* __restrict__ Hoff,
                                                   const double* __restrict__ a_off,
                                                   const double* __restrict__ c_off,
                                                   const float* __restrict__ w_off2,
                                                   const float* __restrict__ b_off2,
                                                   float* __restrict__ out_votes, int N) {
  __shared__ __align__(16) char smem[82944];  // > 80 KB -> 1 block/CU
  const int tid = threadIdx.x;

  if (blockIdx.x < 4) {
    // ------------------------------ FPS path ------------------------------
    float4* cpos = (float4*)smem;  // 64 KB
    ulonglong2(*wv)[4] = (ulonglong2(*)[4])(smem + 65536);
    float4(*wc)[4] = (float4(*)[4])(smem + 65792);
    const int b = blockIdx.x;

#define FPS_DECL(J) float x##J, y##J, z##J; double d##J;
    FPS_REP16(FPS_DECL)

#define FPS_INIT(J) { \
    int p = tid + 256 * (J); \
    unsigned idx = topk[(size_t)b * TOPK + p]; \
    size_t base = ((size_t)b * NB_V + idx) * 3; \
    x##J = xyz[base]; y##J = xyz[base + 1]; z##J = xyz[base + 2]; \
    d##J = 1e10; \
    cpos[p] = make_float4(x##J, y##J, z##J, 0.0f); }
    FPS_REP16(FPS_INIT)

    if (tid == 0) {
      wc[0][0] = make_float4(x0, y0, z0, 0.0f);
      fpspos[(size_t)b * FPSK] = 0u;
    }
    __syncthreads();
    float4 s0 = wc[0][0];
    float sx = s0.x, sy = s0.y, sz = s0.z;
    const int lane = tid & 63, wid = tid >> 6;
    const bool hi16 = (lane & 16) != 0;
    const bool hi32 = (lane & 32) != 0;

    for (int it = 1; it < FPSK; ++it) {
      const int par = it & 1;
      double lx = (double)sx, ly = (double)sy, lz = (double)sz;
      unsigned long long cv0, cv1;
      int cp0, cp1;
#define FPS_UPD(J) { \
    double dx = (double)x##J - lx; \
    double dy = (double)y##J - ly; \
    double dz = (double)z##J - lz; \
    double dd = __dadd_rn(__dadd_rn(__dmul_rn(dx, dx), __dmul_rn(dy, dy)), __dmul_rn(dz, dz)); \
    d##J = fmin(d##J, dd); \
    unsigned long long db = (unsigned long long)__double_as_longlong(d##J); \
    if ((J) == 0) { cv0 = db; cp0 = tid; } \
    else if ((J) == 1) { cv1 = db; cp1 = tid + 256; } \
    else if (((J) & 1) == 0) { bool g = db > cv0; cv0 = g ? db : cv0; cp0 = g ? (tid + 256 * (J)) : cp0; } \
    else { bool g = db > cv1; cv1 = g ? db : cv1; cp1 = g ? (tid + 256 * (J)) : cp1; } }
      FPS_REP16(FPS_UPD)
      {  // merge odd chain into even (tie -> min pos)
        bool g = (cv1 > cv0) || (cv1 == cv0 && cp1 < cp0);
        cv0 = g ? cv1 : cv0;
        cp0 = g ? cp1 : cp0;
      }
      dpp_merge2<0xB1>(cv0, cp0);   // quad_perm xor1
      dpp_merge2<0x4E>(cv0, cp0);   // quad_perm xor2
      dpp_merge2<0x124>(cv0, cp0);  // row_ror:4
      dpp_merge2<0x128>(cv0, cp0);  // row_ror:8 -> row winner in all 16 lanes
      pl16_merge(cv0, cp0, hi16);   // xor16 via v_permlane16_swap (VALU)
      pl32_merge(cv0, cp0, hi32);   // xor32 via v_permlane32_swap (VALU)
      float4 wpos = cpos[cp0];      // uniform addr -> broadcast ds_read_b128
      if (lane == 0) {
        wv[par][wid] = make_ulonglong2(cv0, (unsigned long long)(unsigned)cp0);
        wc[par][wid] = wpos;
      }
      __syncthreads();
      ulonglong2 e0 = wv[par][0];
      float4 q0 = wc[par][0];
      unsigned long long bv = e0.x;
      int bp = (int)e0.y;
      float fx = q0.x, fy = q0.y, fz = q0.z;
#pragma unroll
      for (int w = 1; w < 4; ++w) {
        ulonglong2 e = wv[par][w];
        float4 q = wc[par][w];
        bool t = (e.x > bv) || (e.x == bv && (int)e.y < bp);
        bv = t ? e.x : bv;
        bp = t ? (int)e.y : bp;
        fx = t ? q.x : fx;
        fy = t ? q.y : fy;
        fz = t ? q.z : fz;
      }
      sx = fx; sy = fy; sz = fz;
      if (tid == 0) fpspos[(size_t)b * FPSK + it] = (unsigned)bp;
    }
  } else {
    // --------------------------- fuse_off path ----------------------------
    const int fb = blockIdx.x - 4;  // 0..1023
    double* sa = (double*)smem;
    double* sc = (double*)(smem + 2048);
    double(*w2)[3] = (double(*)[3])(smem + 4096);
    {
      sa[tid] = a_off[tid];
      sc[tid] = c_off[tid];
#pragma unroll
      for (int k = 0; k < 3; ++k) w2[tid][k] = (double)w_off2[tid * 3 + k];
    }
    __syncthreads();
    const int lane = tid & 63, wid = tid >> 6;
    const int gw = fb * 4 + wid;
    for (int r = gw; r < N; r += 4096) {
      double po0 = 0, po1 = 0, po2 = 0;
#pragma unroll
      for (int q = 0; q < 4; ++q) {
        int c = lane + 64 * q;
        double h = (double)Hoff[(size_t)r * 256 + c];
        double v = fma(h, sa[c], sc[c]);
        v = v > 0.0 ? v : 0.0;
        po0 = fma(v, w2[c][0], po0);
        po1 = fma(v, w2[c][1], po1);
        po2 = fma(v, w2[c][2], po2);
      }
#pragma unroll
      for (int off = 32; off; off >>= 1) {
        po0 += __shfl_xor(po0, off);
        po1 += __shfl_xor(po1, off);
        po2 += __shfl_xor(po2, off);
      }
      if (lane == 0) {
        float x = xyz[(size_t)r * 3], y = xyz[(size_t)r * 3 + 1], z = xyz[(size_t)r * 3 + 2];
        float bs = (float)(r >> 16);
        double offv[3] = {po0 + (double)b_off2[0], po1 + (double)b_off2[1], po2 + (double)b_off2[2]};
        const double rng[3] = {3.0, 3.0, 2.0};
        float pxyz[3] = {x, y, z};
        out_votes[(size_t)r * 4 + 0] = bs;
#pragma unroll
        for (int k = 0; k < 3; ++k) {
          double lim = offv[k];
          lim = lim < -rng[k] ? -rng[k] : lim;
          lim = lim > rng[k] ? rng[k] : lim;
          out_votes[(size_t)r * 4 + 1 + k] = (float)((double)pxyz[k] + lim);
        }
      }
    }
  }
}

// ---------------------------------------------------------------------------
// Final gather: fps_indices (as float), vote_candidates, vote_features.
// ---------------------------------------------------------------------------
__global__ __launch_bounds__(256) void k_gather(const unsigned int* __restrict__ topk,
                                                const unsigned int* __restrict__ fpspos,
                                                const float* __restrict__ feats,
                                                const float* __restrict__ votes_out,
                                                float* __restrict__ o0, float* __restrict__ o1,
                                                float* __restrict__ o5) {
  const int r = blockIdx.x;
  const int b = r / FPSK;
  __shared__ unsigned int gsh;
  if (threadIdx.x == 0) {
    unsigned pos = fpspos[r];
    unsigned local = topk[(size_t)b * TOPK + pos];
    gsh = (unsigned)(b * NB_V) + local;
  }
  __syncthreads();
  const unsigned g = gsh;
  o1[(size_t)r * 256 + threadIdx.x] = feats[(size_t)g * 256 + threadIdx.x];
  if (threadIdx.x < 4) o0[(size_t)r * 4 + threadIdx.x] = votes_out[(size_t)g * 4 + threadIdx.x];
  if (threadIdx.x == 4) o5[r] = (float)g;
}

// ---------------------------------------------------------------------------
extern "C" void kernel_launch(void* const* d_in, const int* in_sizes, int n_in,
                              void* d_out, int out_size, void* d_ws, size_t ws_size,
                              hipStream_t stream) {
  const float* xyz = (const float*)d_in[0];
  const float* feats = (const float*)d_in[1];
  const float* w_off1 = (const float*)d_in[2];
  const float* g_off1 = (const float*)d_in[3];
  const float* be_off1 = (const float*)d_in[4];
  const float* w_off2 = (const float*)d_in[5];
  const float* b_off2 = (const float*)d_in[6];
  const float* w_cls1 = (const float*)d_in[7];
  const float* g_cls1 = (const float*)d_in[8];
  const float* be_cls1 = (const float*)d_in[9];
  const float* w_cls2 = (const float*)d_in[10];
  const float* b_cls2 = (const float*)d_in[11];

  const int N = in_sizes[0] / 3;
  const int B = N / NB_V;
  const int BP = B * FPSK;

  float* out = (float*)d_out;
  float* o0 = out;                           // vote_candidates (BP,4)
  float* o1 = o0 + (size_t)BP * 4;           // vote_features   (BP,256)
  float* o2 = o1 + (size_t)BP * 256;         // seeds           (N,4)
  float* o3 = o2 + (size_t)N * 4;            // seed_cls        (N,3)
  float* o4 = o3 + (size_t)N * 3;            // votes           (N,4)
  float* o5 = o4 + (size_t)N * 4;            // fps_indices     (BP,)

  char* w = (char*)d_ws;
  float* Hoff = (float*)w;                           // N*1024 B
  float* Hcls = (float*)(w + (size_t)N * 1024);      // N*1024 B
  char* p0 = w + (size_t)N * 2048;
  double* part_cls = (double*)p0;                    // 16 MB
  float2* part_off = (float2*)(p0 + 16777216);       // 8 MB
  char* p1 = p0 + 16777216 + 8388608;
  double* a_cls = (double*)p1;
  double* c_cls = a_cls + 256;
  double* a_off = c_cls + 256;
  double* c_off = a_off + 256;
  unsigned long long* keys = (unsigned long long*)(p1 + 8192);   // N*8
  unsigned int* topkbuf = (unsigned int*)((char*)keys + (size_t)N * 8);
  unsigned int* fpspos = topkbuf + (size_t)B * TOPK;

  const int NCB = (N / 64) * 2;
  const int NGB = (N / 64) * 4;
  k_dualgemm<<<dim3(NCB + NGB), dim3(256), 0, stream>>>(feats, w_cls1, w_off1, Hcls, Hoff,
                                                        part_cls, part_off, N);
  k_fins<<<dim3(512), dim3(256), 0, stream>>>(part_cls, part_off, g_cls1, be_cls1,
                                              g_off1, be_off1, a_cls, c_cls, a_off, c_off, N);
  k_fuse_cls<<<dim3(1024), dim3(256), 0, stream>>>(Hcls, xyz, w_cls2, b_cls2, a_cls, c_cls,
                                                   o2, o3, keys, N);
  k_topk<<<dim3(B), dim3(1024), 0, stream>>>(keys, topkbuf);
  k_fused2<<<dim3(4 + 1024), dim3(256), 0, stream>>>(xyz, topkbuf, fpspos, Hoff, a_off,
                                                     c_off, w_off2, b_off2, o4, N);
  k_gather<<<dim3(BP), dim3(256), 0, stream>>>(topkbuf, fpspos, feats, o4, o0, o1, o5);
}

// Round 16
// 3428.582 us; speedup vs baseline: 1.2121x; 1.0049x over previous
//
#include <hip/hip_runtime.h>

#define NB_V 65536
#define TOPK 4096
#define FPSK 2048

typedef short bf16x8 __attribute__((ext_vector_type(8)));
typedef float f32x4 __attribute__((ext_vector_type(4)));
typedef unsigned int u32x2 __attribute__((ext_vector_type(2)));

// ---------------------------------------------------------------------------
// DUAL GEMM with INTERLEAVED role mapping: bid%3==0 -> cls f64 GEMM block,
// else -> offset bf16-MFMA block (NCB:NGB == 1:2 by construction). This makes
// f64-VALU and MFMA blocks co-resident on each CU so the pipes overlap
// (in-order dispatch previously serialized the two phases).
// Per-block math identical to validated R13-R15.
// ---------------------------------------------------------------------------
__global__ __launch_bounds__(256, 2) void k_dualgemm(
    const float* __restrict__ A, const float* __restrict__ Wcls,
    const float* __restrict__ Woff, float* __restrict__ Hcls,
    float* __restrict__ Hoff, double* __restrict__ part_cls,
    float2* __restrict__ part_off, int N) {
  __shared__ __align__(16) char smem[67584];
  const int tid = threadIdx.x;
  const int bid = blockIdx.x;

  if (bid % 3 == 0) {
    // ----------------------------- cls f64 GEMM ---------------------------
    const int cbid = bid / 3;                          // 0 .. NCB-1
    double(*Asm)[33] = (double(*)[33])smem;            // [64][33] f64
    double* BfF = (double*)(smem + 16896);             // [32][160] f64
    const int tx = tid & 15, ty = tid >> 4;
    const int cb = cbid & 1;
    const int rb = cbid >> 1;
    double acc[4][8];
#pragma unroll
    for (int i = 0; i < 4; ++i)
#pragma unroll
      for (int j = 0; j < 8; ++j) acc[i][j] = 0.0;

    for (int kc = 0; kc < 256; kc += 32) {
#pragma unroll
      for (int l = 0; l < 8; ++l) {
        int f = tid + 256 * l;
        int r = f >> 5, c = f & 31;
        Asm[r][c] = (double)A[(size_t)(rb * 64 + r) * 256 + kc + c];
      }
#pragma unroll
      for (int l = 0; l < 16; ++l) {
        int f = tid + 256 * l;
        int kr = f >> 7, c = f & 127;
        BfF[kr * 160 + (c >> 3) * 10 + (c & 7)] =
            (double)Wcls[(size_t)(kc + kr) * 256 + cb * 128 + c];
      }
      __syncthreads();
#pragma unroll 4
      for (int kk = 0; kk < 32; ++kk) {
        double a0[4];
#pragma unroll
        for (int i = 0; i < 4; ++i) a0[i] = Asm[ty + 16 * i][kk];
        const double* bR = BfF + kk * 160 + tx * 10;
        double2 b01 = *reinterpret_cast<const double2*>(bR);
        double2 b23 = *reinterpret_cast<const double2*>(bR + 2);
        double2 b45 = *reinterpret_cast<const double2*>(bR + 4);
        double2 b67 = *reinterpret_cast<const double2*>(bR + 6);
        double b0[8] = {b01.x, b01.y, b23.x, b23.y, b45.x, b45.y, b67.x, b67.y};
#pragma unroll
        for (int i = 0; i < 4; ++i)
#pragma unroll
          for (int j = 0; j < 8; ++j) acc[i][j] = fma(a0[i], b0[j], acc[i][j]);
      }
      __syncthreads();
    }
    double s[8], q[8];
#pragma unroll
    for (int j = 0; j < 8; ++j) { s[j] = 0.0; q[j] = 0.0; }
#pragma unroll
    for (int i = 0; i < 4; ++i) {
      float hv[8];
#pragma unroll
      for (int j = 0; j < 8; ++j) {
        hv[j] = (float)acc[i][j];
        double d = (double)hv[j];
        s[j] += d;
        q[j] = fma(d, d, q[j]);
      }
      size_t base = (size_t)(rb * 64 + ty + 16 * i) * 256 + cb * 128 + tx * 8;
      *reinterpret_cast<float4*>(&Hcls[base]) = make_float4(hv[0], hv[1], hv[2], hv[3]);
      *reinterpret_cast<float4*>(&Hcls[base + 4]) = make_float4(hv[4], hv[5], hv[6], hv[7]);
    }
    __syncthreads();  // reuse LDS
    double(*ps)[128] = (double(*)[128])smem;
    double(*pq)[128] = (double(*)[128])(smem + 16384);
#pragma unroll
    for (int j = 0; j < 8; ++j) {
      ps[ty][tx * 8 + j] = s[j];
      pq[ty][tx * 8 + j] = q[j];
    }
    __syncthreads();
    if (tid < 128) {
      double S = 0.0, Q = 0.0;
#pragma unroll
      for (int t = 0; t < 16; ++t) { S += ps[t][tid]; Q += pq[t][tid]; }
      part_cls[(size_t)cbid * 256 + tid * 2] = S;
      part_cls[(size_t)cbid * 256 + tid * 2 + 1] = Q;
    }
  } else {
    // --------------------- offset bf16 GEMM (validated) -------------------
    const int gb = bid - bid / 3 - 1;                  // 0 .. NGB-1 (bijective)
    unsigned short(*As)[264] = (unsigned short(*)[264])smem;
    unsigned short(*Bs)[264] = (unsigned short(*)[264])(smem + 33792);
    const int cb = gb & 3;
    const int rb = gb >> 2;
#pragma unroll
    for (int l = 0; l < 16; ++l) {
      int f = tid + 256 * l;
      int r = f >> 6, c4 = (f & 63) << 2;
      float4 v = *reinterpret_cast<const float4*>(&A[(size_t)(rb * 64 + r) * 256 + c4]);
      ushort4 u;
      u.x = (unsigned short)(__float_as_uint(v.x) >> 16);
      u.y = (unsigned short)(__float_as_uint(v.y) >> 16);
      u.z = (unsigned short)(__float_as_uint(v.z) >> 16);
      u.w = (unsigned short)(__float_as_uint(v.w) >> 16);
      *reinterpret_cast<ushort4*>(&As[r][c4]) = u;
    }
    {
      const int c = tid & 63;
      const int kg = tid >> 6;
#pragma unroll
      for (int j = 0; j < 16; ++j) {
        int k0 = kg * 64 + j * 4;
        ushort4 u;
        u.x = (unsigned short)(__float_as_uint(Woff[(size_t)(k0 + 0) * 256 + cb * 64 + c]) >> 16);
        u.y = (unsigned short)(__float_as_uint(Woff[(size_t)(k0 + 1) * 256 + cb * 64 + c]) >> 16);
        u.z = (unsigned short)(__float_as_uint(Woff[(size_t)(k0 + 2) * 256 + cb * 64 + c]) >> 16);
        u.w = (unsigned short)(__float_as_uint(Woff[(size_t)(k0 + 3) * 256 + cb * 64 + c]) >> 16);
        *reinterpret_cast<ushort4*>(&Bs[c][k0]) = u;
      }
    }
    __syncthreads();
    const int lane = tid & 63, w = tid >> 6;
    const int m = lane & 15, kq = lane >> 4;
    f32x4 acc[4];
#pragma unroll
    for (int s = 0; s < 4; ++s) acc[s] = (f32x4){0.f, 0.f, 0.f, 0.f};
#pragma unroll
    for (int k0 = 0; k0 < 256; k0 += 32) {
      bf16x8 a = *reinterpret_cast<const bf16x8*>(&As[w * 16 + m][k0 + kq * 8]);
#pragma unroll
      for (int s = 0; s < 4; ++s) {
        bf16x8 bfr = *reinterpret_cast<const bf16x8*>(&Bs[s * 16 + m][k0 + kq * 8]);
        acc[s] = __builtin_amdgcn_mfma_f32_16x16x32_bf16(a, bfr, acc[s], 0, 0, 0);
      }
    }
    double cs[4], cq[4];
#pragma unroll
    for (int s = 0; s < 4; ++s) { cs[s] = 0.0; cq[s] = 0.0; }
#pragma unroll
    for (int s = 0; s < 4; ++s)
#pragma unroll
      for (int i = 0; i < 4; ++i) {
        float hv = acc[s][i];
        Hoff[(size_t)(rb * 64 + w * 16 + kq * 4 + i) * 256 + cb * 64 + s * 16 + m] = hv;
        double d = (double)hv;
        cs[s] += d;
        cq[s] = fma(d, d, cq[s]);
      }
    __syncthreads();  // reuse LDS
    double(*ps)[64] = (double(*)[64])smem;
    double(*pq)[64] = (double(*)[64])(smem + 8192);
#pragma unroll
    for (int s = 0; s < 4; ++s) {
      ps[w * 4 + kq][s * 16 + m] = cs[s];
      pq[w * 4 + kq][s * 16 + m] = cq[s];
    }
    __syncthreads();
    if (tid < 64) {
      double S = 0.0, Q = 0.0;
#pragma unroll
      for (int t = 0; t < 16; ++t) { S += ps[t][tid]; Q += pq[t][tid]; }
      part_off[(size_t)gb * 64 + tid] = make_float2((float)S, (float)Q);
    }
  }
}

// ---------------------------------------------------------------------------
// Stats finalize, parallel (validated R12).
// ---------------------------------------------------------------------------
__global__ __launch_bounds__(256) void k_fins(const double* __restrict__ part_cls,
                                              const float2* __restrict__ part_off,
                                              const float* __restrict__ g_cls,
                                              const float* __restrict__ be_cls,
                                              const float* __restrict__ g_off,
                                              const float* __restrict__ be_off,
                                              double* __restrict__ a_cls,
                                              double* __restrict__ c_cls,
                                              double* __restrict__ a_off,
                                              double* __restrict__ c_off, int N) {
  __shared__ double ls[256], lq[256];
  const int tid = threadIdx.x;
  const int nrb = N >> 6;
  double S = 0.0, Q = 0.0;
  if ((int)blockIdx.x < 256) {
    const int c = blockIdx.x;
    const int cbb = c >> 7, cl = c & 127;
    for (int m = 0; m < nrb / 256; ++m) {
      int rb = tid + 256 * m;
      const double* p = part_cls + ((size_t)(rb * 2 + cbb) * 256 + cl * 2);
      S += p[0];
      Q += p[1];
    }
  } else {
    const int c = blockIdx.x - 256;
    const int ccb = c >> 6, cl = c & 63;
    for (int m = 0; m < nrb / 256; ++m) {
      int r2 = tid + 256 * m;
      float2 p = part_off[(size_t)(r2 * 4 + ccb) * 64 + cl];
      S += (double)p.x;
      Q += (double)p.y;
    }
  }
  ls[tid] = S;
  lq[tid] = Q;
  __syncthreads();
  for (int st = 128; st; st >>= 1) {
    if (tid < st) {
      ls[tid] += ls[tid + st];
      lq[tid] += lq[tid + st];
    }
    __syncthreads();
  }
  if (tid == 0) {
    double mean = ls[0] / (double)N;
    double var = lq[0] / (double)N - mean * mean;
    if ((int)blockIdx.x < 256) {
      const int c = blockIdx.x;
      double a = (double)g_cls[c] / sqrt(var + 1e-5);
      a_cls[c] = a;
      c_cls[c] = (double)be_cls[c] - mean * a;
    } else {
      const int c = blockIdx.x - 256;
      double a = (double)g_off[c] / sqrt(var + 1e-5);
      a_off[c] = a;
      c_off[c] = (double)be_off[c] - mean * a;
    }
  }
}

// ---------------------------------------------------------------------------
// cls-side fuse: BN+ReLU+layer2 on Hcls -> seeds, seed_cls, sort keys.
// ---------------------------------------------------------------------------
__global__ __launch_bounds__(256) void k_fuse_cls(const float* __restrict__ Hcls,
                                                  const float* __restrict__ xyz,
                                                  const float* __restrict__ w_cls2,
                                                  const float* __restrict__ b_cls2,
                                                  const double* __restrict__ aarr,
                                                  const double* __restrict__ carr,
                                                  float* __restrict__ out_seeds,
                                                  float* __restrict__ out_cls,
                                                  unsigned long long* __restrict__ keys,
                                                  int N) {
  __shared__ double sa[256], sc[256];
  __shared__ double w2[256][3];
  const int tid = threadIdx.x;
  {
    sa[tid] = aarr[tid];
    sc[tid] = carr[tid];
#pragma unroll
    for (int k = 0; k < 3; ++k) w2[tid][k] = (double)w_cls2[tid * 3 + k];
  }
  __syncthreads();
  const int lane = tid & 63, wid = tid >> 6;
  const int gw = blockIdx.x * 4 + wid;
  for (int r = gw; r < N; r += 4096) {
    double pc0 = 0, pc1 = 0, pc2 = 0;
#pragma unroll
    for (int q = 0; q < 4; ++q) {
      int c = lane + 64 * q;
      double h2 = (double)Hcls[(size_t)r * 256 + c];
      double v2 = fma(h2, sa[c], sc[c]);
      v2 = v2 > 0.0 ? v2 : 0.0;
      pc0 = fma(v2, w2[c][0], pc0);
      pc1 = fma(v2, w2[c][1], pc1);
      pc2 = fma(v2, w2[c][2], pc2);
    }
#pragma unroll
    for (int off = 32; off; off >>= 1) {
      pc0 += __shfl_xor(pc0, off);
      pc1 += __shfl_xor(pc1, off);
      pc2 += __shfl_xor(pc2, off);
    }
    if (lane == 0) {
      float x = xyz[(size_t)r * 3], y = xyz[(size_t)r * 3 + 1], z = xyz[(size_t)r * 3 + 2];
      float bs = (float)(r >> 16);
      out_seeds[(size_t)r * 4 + 0] = bs;
      out_seeds[(size_t)r * 4 + 1] = x;
      out_seeds[(size_t)r * 4 + 2] = y;
      out_seeds[(size_t)r * 4 + 3] = z;
      double c0 = pc0 + (double)b_cls2[0];
      double c1 = pc1 + (double)b_cls2[1];
      double c2v = pc2 + (double)b_cls2[2];
      out_cls[(size_t)r * 3 + 0] = (float)c0;
      out_cls[(size_t)r * 3 + 1] = (float)c1;
      out_cls[(size_t)r * 3 + 2] = (float)c2v;
      double s = c0 > c1 ? c0 : c1;
      s = s > c2v ? s : c2v;
      long long bits = __double_as_longlong(s);
      unsigned long long key =
          bits >= 0 ? ((unsigned long long)bits | 0x8000000000000000ull) : ~((unsigned long long)bits);
      keys[r] = key;
    }
  }
}

// ---------------------------------------------------------------------------
// Per-batch top-4096 radix select + bitonic sort (validated).
// ---------------------------------------------------------------------------
__global__ __launch_bounds__(1024) void k_topk(const unsigned long long* __restrict__ keys,
                                               unsigned int* __restrict__ topk) {
  const int b = blockIdx.x;
  const unsigned long long* K = keys + (size_t)b * NB_V;
  __shared__ unsigned int hist[256];
  __shared__ unsigned long long pfx_s;
  __shared__ int want_s;
  __shared__ unsigned long long skey[TOPK];
  __shared__ unsigned int sidx[TOPK];
  __shared__ int cnt_hi, cnt_eq;
  __shared__ unsigned int eq_idx[1024];
  const int tid = threadIdx.x;
  const int lane = tid & 63;
  if (tid == 0) { pfx_s = 0ull; want_s = TOPK; }
  __syncthreads();
  for (int p = 0; p < 8; ++p) {
    const int shift = 56 - 8 * p;
    if (tid < 256) hist[tid] = 0;
    __syncthreads();
    unsigned long long pfx = pfx_s;
    for (int i = tid; i < NB_V; i += 1024) {
      unsigned long long k = K[i];
      bool ok;
      if (p == 0) ok = true;
      else ok = ((k >> (shift + 8)) == (pfx >> (shift + 8)));
      unsigned bin = ok ? (unsigned)((k >> shift) & 255u) : 0xFFFFFFFFu;
      unsigned long long okm = __ballot(ok);
      if (okm) {
        int leader = __ffsll((unsigned long long)okm) - 1;
        unsigned pb = __shfl(bin, leader);
        unsigned long long m = __ballot(ok && bin == pb);
        if (lane == leader) atomicAdd(&hist[pb], (unsigned)__popcll(m));
        if (ok && bin != pb) atomicAdd(&hist[bin], 1u);
      }
    }
    __syncthreads();
    if (tid == 0) {
      int want = want_s;
      int cum = 0, d = 255;
      for (; d >= 0; --d) {
        int c = (int)hist[d];
        if (cum + c >= want) break;
        cum += c;
      }
      want_s = want - cum;
      pfx_s = pfx_s | ((unsigned long long)d << shift);
    }
    __syncthreads();
  }
  const unsigned long long Kthr = pfx_s;
  const int T = want_s;
  if (tid == 0) { cnt_hi = 0; cnt_eq = 0; }
  __syncthreads();
  for (int i = tid; i < NB_V; i += 1024) {
    unsigned long long k = K[i];
    if (k > Kthr) {
      int pos = atomicAdd(&cnt_hi, 1);
      skey[pos] = k;
      sidx[pos] = (unsigned)i;
    } else if (k == Kthr) {
      int pos = atomicAdd(&cnt_eq, 1);
      if (pos < 1024) eq_idx[pos] = (unsigned)i;
    }
  }
  __syncthreads();
  if (tid == 0) {
    int m = cnt_eq; if (m > 1024) m = 1024;
    for (int a2 = 1; a2 < m; ++a2) {
      unsigned v = eq_idx[a2];
      int b2 = a2 - 1;
      while (b2 >= 0 && eq_idx[b2] > v) { eq_idx[b2 + 1] = eq_idx[b2]; --b2; }
      eq_idx[b2 + 1] = v;
    }
    for (int t = 0; t < T; ++t) { skey[cnt_hi + t] = Kthr; sidx[cnt_hi + t] = eq_idx[t]; }
  }
  __syncthreads();
  for (int k2 = 2; k2 <= TOPK; k2 <<= 1) {
    for (int j = k2 >> 1; j > 0; j >>= 1) {
      for (int i = tid; i < TOPK; i += 1024) {
        int ix = i ^ j;
        if (ix > i) {
          unsigned long long ka = skey[i], kb = skey[ix];
          unsigned int ia = sidx[i], ib = sidx[ix];
          bool a_first = (ka > kb) || (ka == kb && ia < ib);
          bool up = (i & k2) == 0;
          if (up ? !a_first : a_first) {
            skey[i] = kb; skey[ix] = ka;
            sidx[i] = ib; sidx[ix] = ia;
          }
        }
      }
      __syncthreads();
    }
  }
  for (int i = tid; i < TOPK; i += 1024) topk[(size_t)b * TOPK + i] = sidx[i];
}

// ---------------------------------------------------------------------------
// FUSED2 (frozen, validated R15): blocks 0..3 = D-FPS (256 thr x 16 pts,
// DPP + permlane16/32_swap reduce); blocks 4..1027 = fuse_off.
// 82944 B LDS -> 1 block/CU.
// ---------------------------------------------------------------------------
template <int CTRL>
__device__ __forceinline__ void dpp_merge2(unsigned long long& v, int& p) {
  unsigned lo = (unsigned)v, hi = (unsigned)(v >> 32);
  unsigned olo = (unsigned)__builtin_amdgcn_update_dpp(0, (int)lo, CTRL, 0xF, 0xF, false);
  unsigned ohi = (unsigned)__builtin_amdgcn_update_dpp(0, (int)hi, CTRL, 0xF, 0xF, false);
  int op = __builtin_amdgcn_update_dpp(0, p, CTRL, 0xF, 0xF, false);
  unsigned long long ov = ((unsigned long long)ohi << 32) | (unsigned long long)olo;
  bool t = (ov > v) || (ov == v && op < p);
  v = t ? ov : v;
  p = t ? op : p;
}

__device__ __forceinline__ unsigned pl16x(unsigned v, bool hi16) {
  u32x2 r = __builtin_amdgcn_permlane16_swap(v, v, false, false);
  return hi16 ? r.x : r.y;
}
__device__ __forceinline__ unsigned pl32x(unsigned v, bool hi32) {
  u32x2 r = __builtin_amdgcn_permlane32_swap(v, v, false, false);
  return hi32 ? r.x : r.y;
}

__device__ __forceinline__ void pl16_merge(unsigned long long& v, int& p, bool hi16) {
  unsigned olo = pl16x((unsigned)v, hi16);
  unsigned ohi = pl16x((unsigned)(v >> 32), hi16);
  int op = (int)pl16x((unsigned)p, hi16);
  unsigned long long ov = ((unsigned long long)ohi << 32) | (unsigned long long)olo;
  bool t = (ov > v) || (ov == v && op < p);
  v = t ? ov : v;
  p = t ? op : p;
}
__device__ __forceinline__ void pl32_merge(unsigned long long& v, int& p, bool hi32) {
  unsigned olo = pl32x((unsigned)v, hi32);
  unsigned ohi = pl32x((unsigned)(v >> 32), hi32);
  int op = (int)pl32x((unsigned)p, hi32);
  unsigned long long ov = ((unsigned long long)ohi << 32) | (unsigned long long)olo;
  bool t = (ov > v) || (ov == v && op < p);
  v = t ? ov : v;
  p = t ? op : p;
}

#define FPS_REP16(M) M(0) M(1) M(2) M(3) M(4) M(5) M(6) M(7) \
                     M(8) M(9) M(10) M(11) M(12) M(13) M(14) M(15)

__global__ __launch_bounds__(256, 1) void k_fused2(const float* __restrict__ xyz,
                                                   const unsigned int* __restrict__ topk,
                                                   unsigned int* __restrict__ fpspos,
                                                   const float* __restrict__ Hoff,
                                                   const double* __restrict__ a_off,
                                                   const double* __restrict__ c_off,
                                                   const float* __restrict__ w_off2,
                                                   const float* __restrict__ b_off2,
                                                   float* __restrict__ out_votes, int N) {
  __shared__ __align__(16) char smem[82944];  // > 80 KB -> 1 block/CU
  const int tid = threadIdx.x;

  if (blockIdx.x < 4) {
    // ------------------------------ FPS path ------------------------------
    float4* cpos = (float4*)smem;  // 64 KB
    ulonglong2(*wv)[4] = (ulonglong2(*)[4])(smem + 65536);
    float4(*wc)[4] = (float4(*)[4])(smem + 65792);
    const int b = blockIdx.x;

#define FPS_DECL(J) float x##J, y##J, z##J; double d##J;
    FPS_REP16(FPS_DECL)

#define FPS_INIT(J) { \
    int p = tid + 256 * (J); \
    unsigned idx = topk[(size_t)b * TOPK + p]; \
    size_t base = ((size_t)b * NB_V + idx) * 3; \
    x##J = xyz[base]; y##J = xyz[base + 1]; z##J = xyz[base + 2]; \
    d##J = 1e10; \
    cpos[p] = make_float4(x##J, y##J, z##J, 0.0f); }
    FPS_REP16(FPS_INIT)

    if (tid == 0) {
      wc[0][0] = make_float4(x0, y0, z0, 0.0f);
      fpspos[(size_t)b * FPSK] = 0u;
    }
    __syncthreads();
    float4 s0 = wc[0][0];
    float sx = s0.x, sy = s0.y, sz = s0.z;
    const int lane = tid & 63, wid = tid >> 6;
    const bool hi16 = (lane & 16) != 0;
    const bool hi32 = (lane & 32) != 0;

    for (int it = 1; it < FPSK; ++it) {
      const int par = it & 1;
      double lx = (double)sx, ly = (double)sy, lz = (double)sz;
      unsigned long long cv0, cv1;
      int cp0, cp1;
#define FPS_UPD(J) { \
    double dx = (double)x##J - lx; \
    double dy = (double)y##J - ly; \
    double dz = (double)z##J - lz; \
    double dd = __dadd_rn(__dadd_rn(__dmul_rn(dx, dx), __dmul_rn(dy, dy)), __dmul_rn(dz, dz)); \
    d##J = fmin(d##J, dd); \
    unsigned long long db = (unsigned long long)__double_as_longlong(d##J); \
    if ((J) == 0) { cv0 = db; cp0 = tid; } \
    else if ((J) == 1) { cv1 = db; cp1 = tid + 256; } \
    else if (((J) & 1) == 0) { bool g = db > cv0; cv0 = g ? db : cv0; cp0 = g ? (tid + 256 * (J)) : cp0; } \
    else { bool g = db > cv1; cv1 = g ? db : cv1; cp1 = g ? (tid + 256 * (J)) : cp1; } }
      FPS_REP16(FPS_UPD)
      {  // merge odd chain into even (tie -> min pos)
        bool g = (cv1 > cv0) || (cv1 == cv0 && cp1 < cp0);
        cv0 = g ? cv1 : cv0;
        cp0 = g ? cp1 : cp0;
      }
      dpp_merge2<0xB1>(cv0, cp0);   // quad_perm xor1
      dpp_merge2<0x4E>(cv0, cp0);   // quad_perm xor2
      dpp_merge2<0x124>(cv0, cp0);  // row_ror:4
      dpp_merge2<0x128>(cv0, cp0);  // row_ror:8 -> row winner in all 16 lanes
      pl16_merge(cv0, cp0, hi16);   // xor16 via v_permlane16_swap (VALU)
      pl32_merge(cv0, cp0, hi32);   // xor32 via v_permlane32_swap (VALU)
      float4 wpos = cpos[cp0];      // uniform addr -> broadcast ds_read_b128
      if (lane == 0) {
        wv[par][wid] = make_ulonglong2(cv0, (unsigned long long)(unsigned)cp0);
        wc[par][wid] = wpos;
      }
      __syncthreads();
      ulonglong2 e0 = wv[par][0];
      float4 q0 = wc[par][0];
      unsigned long long bv = e0.x;
      int bp = (int)e0.y;
      float fx = q0.x, fy = q0.y, fz = q0.z;
#pragma unroll
      for (int w = 1; w < 4; ++w) {
        ulonglong2 e = wv[par][w];
        float4 q = wc[par][w];
        bool t = (e.x > bv) || (e.x == bv && (int)e.y < bp);
        bv = t ? e.x : bv;
        bp = t ? (int)e.y : bp;
        fx = t ? q.x : fx;
        fy = t ? q.y : fy;
        fz = t ? q.z : fz;
      }
      sx = fx; sy = fy; sz = fz;
      if (tid == 0) fpspos[(size_t)b * FPSK + it] = (unsigned)bp;
    }
  } else {
    // --------------------------- fuse_off path ----------------------------
    const int fb = blockIdx.x - 4;  // 0..1023
    double* sa = (double*)smem;
    double* sc = (double*)(smem + 2048);
    double(*w2)[3] = (double(*)[3])(smem + 4096);
    {
      sa[tid] = a_off[tid];
      sc[tid] = c_off[tid];
#pragma unroll
      for (int k = 0; k < 3; ++k) w2[tid][k] = (double)w_off2[tid * 3 + k];
    }
    __syncthreads();
    const int lane = tid & 63, wid = tid >> 6;
    const int gw = fb * 4 + wid;
    for (int r = gw; r < N; r += 4096) {
      double po0 = 0, po1 = 0, po2 = 0;
#pragma unroll
      for (int q = 0; q < 4; ++q) {
        int c = lane + 64 * q;
        double h = (double)Hoff[(size_t)r * 256 + c];
        double v = fma(h, sa[c], sc[c]);
        v = v > 0.0 ? v : 0.0;
        po0 = fma(v, w2[c][0], po0);
        po1 = fma(v, w2[c][1], po1);
        po2 = fma(v, w2[c][2], po2);
      }
#pragma unroll
      for (int off = 32; off; off >>= 1) {
        po0 += __shfl_xor(po0, off);
        po1 += __shfl_xor(po1, off);
        po2 += __shfl_xor(po2, off);
      }
      if (lane == 0) {
        float x = xyz[(size_t)r * 3], y = xyz[(size_t)r * 3 + 1], z = xyz[(size_t)r * 3 + 2];
        float bs = (float)(r >> 16);
        double offv[3] = {po0 + (double)b_off2[0], po1 + (double)b_off2[1], po2 + (double)b_off2[2]};
        const double rng[3] = {3.0, 3.0, 2.0};
        float pxyz[3] = {x, y, z};
        out_votes[(size_t)r * 4 + 0] = bs;
#pragma unroll
        for (int k = 0; k < 3; ++k) {
          double lim = offv[k];
          lim = lim < -rng[k] ? -rng[k] : lim;
          lim = lim > rng[k] ? rng[k] : lim;
          out_votes[(size_t)r * 4 + 1 + k] = (float)((double)pxyz[k] + lim);
        }
      }
    }
  }
}

// ---------------------------------------------------------------------------
// Final gather: fps_indices (as float), vote_candidates, vote_features.
// ---------------------------------------------------------------------------
__global__ __launch_bounds__(256) void k_gather(const unsigned int* __restrict__ topk,
                                                const unsigned int* __restrict__ fpspos,
                                                const float* __restrict__ feats,
                                                const float* __restrict__ votes_out,
                                                float* __restrict__ o0, float* __restrict__ o1,
                                                float* __restrict__ o5) {
  const int r = blockIdx.x;
  const int b = r / FPSK;
  __shared__ unsigned int gsh;
  if (threadIdx.x == 0) {
    unsigned pos = fpspos[r];
    unsigned local = topk[(size_t)b * TOPK + pos];
    gsh = (unsigned)(b * NB_V) + local;
  }
  __syncthreads();
  const unsigned g = gsh;
  o1[(size_t)r * 256 + threadIdx.x] = feats[(size_t)g * 256 + threadIdx.x];
  if (threadIdx.x < 4) o0[(size_t)r * 4 + threadIdx.x] = votes_out[(size_t)g * 4 + threadIdx.x];
  if (threadIdx.x == 4) o5[r] = (float)g;
}

// ---------------------------------------------------------------------------
extern "C" void kernel_launch(void* const* d_in, const int* in_sizes, int n_in,
                              void* d_out, int out_size, void* d_ws, size_t ws_size,
                              hipStream_t stream) {
  const float* xyz = (const float*)d_in[0];
  const float* feats = (const float*)d_in[1];
  const float* w_off1 = (const float*)d_in[2];
  const float* g_off1 = (const float*)d_in[3];
  const float* be_off1 = (const float*)d_in[4];
  const float* w_off2 = (const float*)d_in[5];
  const float* b_off2 = (const float*)d_in[6];
  const float* w_cls1 = (const float*)d_in[7];
  const float* g_cls1 = (const float*)d_in[8];
  const float* be_cls1 = (const float*)d_in[9];
  const float* w_cls2 = (const float*)d_in[10];
  const float* b_cls2 = (const float*)d_in[11];

  const int N = in_sizes[0] / 3;
  const int B = N / NB_V;
  const int BP = B * FPSK;

  float* out = (float*)d_out;
  float* o0 = out;                           // vote_candidates (BP,4)
  float* o1 = o0 + (size_t)BP * 4;           // vote_features   (BP,256)
  float* o2 = o1 + (size_t)BP * 256;         // seeds           (N,4)
  float* o3 = o2 + (size_t)N * 4;            // seed_cls        (N,3)
  float* o4 = o3 + (size_t)N * 3;            // votes           (N,4)
  float* o5 = o4 + (size_t)N * 4;            // fps_indices     (BP,)

  char* w = (char*)d_ws;
  float* Hoff = (float*)w;                           // N*1024 B
  float* Hcls = (float*)(w + (size_t)N * 1024);      // N*1024 B
  char* p0 = w + (size_t)N * 2048;
  double* part_cls = (double*)p0;                    // 16 MB
  float2* part_off = (float2*)(p0 + 16777216);       // 8 MB
  char* p1 = p0 + 16777216 + 8388608;
  double* a_cls = (double*)p1;
  double* c_cls = a_cls + 256;
  double* a_off = c_cls + 256;
  double* c_off = a_off + 256;
  unsigned long long* keys = (unsigned long long*)(p1 + 8192);   // N*8
  unsigned int* topkbuf = (unsigned int*)((char*)keys + (size_t)N * 8);
  unsigned int* fpspos = topkbuf + (size_t)B * TOPK;

  const int NCB = (N / 64) * 2;
  const int NGB = (N / 64) * 4;
  k_dualgemm<<<dim3(NCB + NGB), dim3(256), 0, stream>>>(feats, w_cls1, w_off1, Hcls, Hoff,
                                                        part_cls, part_off, N);
  k_fins<<<dim3(512), dim3(256), 0, stream>>>(part_cls, part_off, g_cls1, be_cls1,
                                              g_off1, be_off1, a_cls, c_cls, a_off, c_off, N);
  k_fuse_cls<<<dim3(1024), dim3(256), 0, stream>>>(Hcls, xyz, w_cls2, b_cls2, a_cls, c_cls,
                                                   o2, o3, keys, N);
  k_topk<<<dim3(B), dim3(1024), 0, stream>>>(keys, topkbuf);
  k_fused2<<<dim3(4 + 1024), dim3(256), 0, stream>>>(xyz, topkbuf, fpspos, Hoff, a_off,
                                                     c_off, w_off2, b_off2, o4, N);
  k_gather<<<dim3(BP), dim3(256), 0, stream>>>(topkbuf, fpspos, feats, o4, o0, o1, o5);
}